// Round 8
// baseline (7260.863 us; speedup 1.0000x reference)
//
#include <hip/hip_runtime.h>
#include <hip/hip_bf16.h>
#include <math.h>

// Problem constants
constexpr int B = 128;
constexpr int T = 256;
constexpr int H = 200;       // hidden
constexpr int G4 = 800;      // 4*H
constexpr int BT = B * T;    // 32768
constexpr int K0 = 360, K0P = 384;   // layer0 input dim, padded to %32
constexpr int K1 = 400, K1P = 416;   // layer1 input dim, padded to %32

typedef __bf16 bf16x8 __attribute__((ext_vector_type(8)));
typedef float f32x4 __attribute__((ext_vector_type(4)));
typedef float f32x2 __attribute__((ext_vector_type(2)));
typedef unsigned short ushortx4 __attribute__((ext_vector_type(4)));

__device__ __forceinline__ float bfr2f(unsigned short u) {
  union { unsigned int i; float f; } x;
  x.i = ((unsigned int)u) << 16;
  return x.f;
}
__device__ __forceinline__ float uif(unsigned u) {
  union { unsigned int i; float f; } x;
  x.i = u;
  return x.f;
}
__device__ __forceinline__ f32x2 up2(unsigned u) {
  f32x2 r;
  r[0] = uif(u << 16);
  r[1] = uif(u & 0xffff0000u);
  return r;
}
__device__ __forceinline__ unsigned short f2bu(float f) {
  __hip_bfloat16 b = __float2bfloat16(f);
  return *(unsigned short*)&b;
}
__device__ __forceinline__ float sigm(float x) {
  return 1.0f / (1.0f + __expf(-x));
}
__device__ __forceinline__ float tanh_f(float x) {
  float e = __expf(2.0f * x);
  return (e - 1.0f) / (e + 1.0f);
}

// ---------------------------------------------------------------------------
// Dtype detector (f32 vs bf16 storage of float inputs); see round-2 notes.
__global__ void detect_dtype(const unsigned short* __restrict__ raw,
                             int* __restrict__ flag) {
  __shared__ int cnt[256];
  int c = 0;
  for (int j = 0; j < 32; ++j) {
    unsigned short u = raw[1024 + threadIdx.x * 32 + j];
    int e = (u >> 7) & 0xFF;
    if (e >= 0xC0) ++c;
  }
  cnt[threadIdx.x] = c;
  __syncthreads();
  for (int off = 128; off > 0; off >>= 1) {
    if (threadIdx.x < off) cnt[threadIdx.x] += cnt[threadIdx.x + off];
    __syncthreads();
  }
  if (threadIdx.x == 0) *flag = (cnt[0] > 16) ? 1 : 0;
}

// Generic convert-to-bf16 (f32 world) or raw copy (bf16 world)
__global__ void conv_to_bf16(const void* __restrict__ src,
                             __hip_bfloat16* __restrict__ dst, int n,
                             const int* __restrict__ flag) {
  int f = *flag;
  int stride = gridDim.x * blockDim.x;
  for (int i = blockIdx.x * blockDim.x + threadIdx.x; i < n; i += stride) {
    if (f) dst[i] = __float2bfloat16(((const float*)src)[i]);
    else   ((unsigned short*)dst)[i] = ((const unsigned short*)src)[i];
  }
}

// ---------------------------------------------------------------------------
// Embedding concat into X0 [BT][K0P]
__global__ void embed_kernel(const int* __restrict__ words,
                             const int* __restrict__ pos,
                             const int* __restrict__ ner,
                             const __hip_bfloat16* __restrict__ embC,
                             const __hip_bfloat16* __restrict__ posC,
                             const __hip_bfloat16* __restrict__ nerC,
                             __hip_bfloat16* __restrict__ X0) {
  int bt = blockIdx.x;
  int w = words[bt], p = pos[bt], nr = ner[bt];
  for (int j = threadIdx.x; j < K0P; j += blockDim.x) {
    __hip_bfloat16 v;
    if (j < 300)       v = embC[(size_t)w * 300 + j];
    else if (j < 330)  v = posC[(size_t)p * 30 + (j - 300)];
    else if (j < 360)  v = nerC[(size_t)nr * 30 + (j - 330)];
    else               v = __float2bfloat16(0.0f);
    X0[(size_t)bt * K0P + j] = v;
  }
}

// Zero the K-pad tail columns [400:416) of X1
__global__ void zero_x1_tail(__hip_bfloat16* __restrict__ X1) {
  int idx = blockIdx.x * blockDim.x + threadIdx.x;  // BT*16 threads
  int bt = idx >> 4, j = idx & 15;
  X1[(size_t)bt * K1P + 400 + j] = __float2bfloat16(0.0f);
}

// Pad-copy a weight matrix [rows,K] -> [rows,Kp] with zero fill (+dtype conv)
__global__ void pad_copy(const void* __restrict__ src,
                         __hip_bfloat16* __restrict__ dst, int K, int Kp,
                         const int* __restrict__ flag) {
  int r = blockIdx.x;
  int f = *flag;
  for (int j = threadIdx.x; j < Kp; j += blockDim.x) {
    __hip_bfloat16 v = __float2bfloat16(0.0f);
    if (j < K)
      v = f ? __float2bfloat16(((const float*)src)[(size_t)r * K + j])
            : ((const __hip_bfloat16*)src)[(size_t)r * K + j];
    dst[(size_t)r * Kp + j] = v;
  }
}

// Pack W_hh [800][200] into k-pairwise dwords: Wpack[n][p] = bf16(w[n][2p]) |
// bf16(w[n][2p+1])<<16.
__global__ void pack_whh(const void* __restrict__ src,
                         unsigned* __restrict__ dst,
                         const int* __restrict__ flag) {
  int idx = blockIdx.x * blockDim.x + threadIdx.x;  // 800*100
  if (idx >= G4 * 100) return;
  int f = *flag;
  int n = idx / 100, p = idx % 100;
  unsigned short lo, hi;
  if (f) {
    lo = f2bu(((const float*)src)[(size_t)n * 200 + 2 * p]);
    hi = f2bu(((const float*)src)[(size_t)n * 200 + 2 * p + 1]);
  } else {
    lo = ((const unsigned short*)src)[(size_t)n * 200 + 2 * p];
    hi = ((const unsigned short*)src)[(size_t)n * 200 + 2 * p + 1];
  }
  dst[idx] = (unsigned)lo | ((unsigned)hi << 16);
}

// ---------------------------------------------------------------------------
// MFMA GEMM: C[M,800] = A[M,Kp] @ Bm[800,Kp]^T   (bf16 in, fp32 acc, bf16 out)
__global__ __launch_bounds__(256) void gemm_bt(
    const __hip_bfloat16* __restrict__ A,
    const __hip_bfloat16* __restrict__ Bm,
    __hip_bfloat16* __restrict__ C,
    int N, int Kp) {
  const int lane = threadIdx.x & 63;
  const int wave = threadIdx.x >> 6;
  const int l15 = lane & 15, quad = lane >> 4;
  const int m0 = blockIdx.x * 64 + (wave & 1) * 32;
  const int n0 = blockIdx.y * 64 + (wave >> 1) * 32;

  f32x4 acc[2][2] = {};

  int c0 = n0 + l15;       if (c0 > N - 1) c0 = N - 1;
  int c1 = n0 + 16 + l15;  if (c1 > N - 1) c1 = N - 1;
  const size_t ar0 = (size_t)(m0 + l15) * Kp;
  const size_t ar1 = (size_t)(m0 + 16 + l15) * Kp;
  const size_t br0 = (size_t)c0 * Kp;
  const size_t br1 = (size_t)c1 * Kp;

  for (int k0 = 0; k0 < Kp; k0 += 32) {
    int ko = k0 + quad * 8;
    bf16x8 a0 = *(const bf16x8*)(A + ar0 + ko);
    bf16x8 a1 = *(const bf16x8*)(A + ar1 + ko);
    bf16x8 b0 = *(const bf16x8*)(Bm + br0 + ko);
    bf16x8 b1 = *(const bf16x8*)(Bm + br1 + ko);
    acc[0][0] = __builtin_amdgcn_mfma_f32_16x16x32_bf16(a0, b0, acc[0][0], 0, 0, 0);
    acc[0][1] = __builtin_amdgcn_mfma_f32_16x16x32_bf16(a0, b1, acc[0][1], 0, 0, 0);
    acc[1][0] = __builtin_amdgcn_mfma_f32_16x16x32_bf16(a1, b0, acc[1][0], 0, 0, 0);
    acc[1][1] = __builtin_amdgcn_mfma_f32_16x16x32_bf16(a1, b1, acc[1][1], 0, 0, 0);
  }
  #pragma unroll
  for (int mi = 0; mi < 2; ++mi)
    #pragma unroll
    for (int ni = 0; ni < 2; ++ni)
      #pragma unroll
      for (int r = 0; r < 4; ++r) {
        int row = m0 + mi * 16 + quad * 4 + r;
        int col = n0 + ni * 16 + l15;
        if (col < N)
          C[(size_t)row * N + col] = __float2bfloat16(acc[mi][ni][r]);
      }
}

// ---------------------------------------------------------------------------
// LSTM recurrence v3: 512 threads, (nearly) ALL weights register-resident.
// grid 256 = dir*128 + row; block 512 (8 waves).
// The 93 KB static LDS forces 1 block/CU (>80 KB) -> 2 waves/SIMD -> the
// allocator's LDS-constrained occupancy gives a 256-VGPR budget (round-7
// verified mechanism; dynamic shmem would NOT work — the heuristic only sees
// static LDS).
// Thread (kq=tid&3, gslot=tid>>2 in [0,128)): k-quarter [kq*50,+50) of gates
// {gslot+128j, j<6} = 150 packed dwords in VGPRs. Tail gates 768..799 come
// from a 12.8 KB LDS strip, handled by gslot>=96 (waves 6-7, wave-uniform) —
// LDS weight traffic/step drops 115 KB -> 12.8 KB (round-7's 62M-conflict,
// ~900 cyc/step LDS-port bottleneck).
// Partials parts[gate*4+kq]: writes uniform 2-way (free, m136); reduce reads
// are canonical contiguous ds_read_b128. 200 reduce threads (waves 0-3, one
// per SIMD) sum 4 partials + bias + Gpre, nonlinearity, h->LDS.
__global__ __launch_bounds__(512, 1) void lstm_row(
    const __hip_bfloat16* __restrict__ Gpre,   // [2][B*T][800]  x@W_ih^T (no bias)
    const unsigned* __restrict__ Wpack,        // [2][800][100] packed k-pairs
    const __hip_bfloat16* __restrict__ bias_f, // [800]
    const __hip_bfloat16* __restrict__ bias_b, // [800]
    const int* __restrict__ masks,             // [B][T], 1 = pad
    __hip_bfloat16* __restrict__ out,          // [B][T][ostride], cols dir*200..+200
    int ostride,
    float* __restrict__ final_h)               // [B][400] = [hb | hf], or nullptr
{
  const int tid = threadIdx.x;
  const int dir = blockIdx.x >> 7;
  const int row = blockIdx.x & 127;
  const int kq = tid & 3;            // k-quarter: k in [kq*50, kq*50+50)
  const int gslot = tid >> 2;        // 0..127
  const bool tail = (gslot >= 96);   // waves 6,7 — wave-uniform

  __shared__ __align__(16) float hsh[200];
  __shared__ __align__(16) float parts[G4 * 4];  // [gate][kq], 12800 B
  __shared__ int msk[T];                         // 1024 B
  __shared__ unsigned wforce[20000];             // 80000 B (first 3200 = tail W)

  const unsigned* wb = Wpack + (size_t)dir * G4 * 100;

  // --- tail-gate weights (768..799) into LDS ---
  for (int i = tid; i < 3200; i += 512) wforce[i] = wb[76800 + i];
  // --- mask row preload ---
  for (int i = tid; i < T; i += 512) msk[i] = masks[row * T + i];

  // --- register weights: 150 dwords/thread (all indices compile-time) ---
  unsigned w[6][25];
  {
    const unsigned* s = wb + gslot * 100 + kq * 25;
    #pragma unroll
    for (int j = 0; j < 6; ++j)
      #pragma unroll
      for (int p = 0; p < 25; ++p)
        w[j][p] = s[12800 * j + p];
  }
  const unsigned* lt = &wforce[(gslot - 96) * 100 + kq * 25];  // valid if tail

  // --- reduce-thread constants (u = hidden unit) ---
  const int u = tid;
  const __hip_bfloat16* bias = dir ? bias_b : bias_f;
  float bI = 0.f, bF = 0.f, bG = 0.f, bO = 0.f;
  if (u < 200) {
    bI = __bfloat162float(bias[u]);
    bF = __bfloat162float(bias[200 + u]);
    bG = __bfloat162float(bias[400 + u]);
    bO = __bfloat162float(bias[600 + u]);
  }

  if (tid < 200) hsh[tid] = 0.0f;
  float creg = 0.0f, hreg = 0.0f;
  __syncthreads();

  const unsigned short* gp = (const unsigned short*)Gpre + (size_t)dir * BT * G4;
  const size_t gbase = (size_t)row * T * G4;

  #pragma unroll 1
  for (int tt = 0; tt < T; ++tt) {
    const int t = dir ? (T - 1 - tt) : tt;
    const size_t goff = gbase + (size_t)t * G4;
    // prefetch gate pre-activations + mask (consumed in the reduce phase)
    unsigned short qI = 0, qF = 0, qG = 0, qO = 0;
    int mk = 0;
    if (u < 200) {
      qI = gp[goff + u];
      qF = gp[goff + 200 + u];
      qG = gp[goff + 400 + u];
      qO = gp[goff + 600 + u];
      mk = msk[t];
    }

    // --- dot phase: register weights x h (LDS broadcast f32x2 reads) ---
    const f32x2* hp = (const f32x2*)hsh + kq * 25;
    f32x2 a0 = {0.f, 0.f}, a1 = {0.f, 0.f}, a2 = {0.f, 0.f};
    f32x2 a3 = {0.f, 0.f}, a4 = {0.f, 0.f}, a5 = {0.f, 0.f};
    #pragma unroll
    for (int p = 0; p < 25; ++p) {
      f32x2 h2 = hp[p];
      a0 += h2 * up2(w[0][p]);
      a1 += h2 * up2(w[1][p]);
      a2 += h2 * up2(w[2][p]);
      a3 += h2 * up2(w[3][p]);
      a4 += h2 * up2(w[4][p]);
      a5 += h2 * up2(w[5][p]);
    }
    parts[(gslot)        * 4 + kq] = a0[0] + a0[1];
    parts[(128 + gslot)  * 4 + kq] = a1[0] + a1[1];
    parts[(256 + gslot)  * 4 + kq] = a2[0] + a2[1];
    parts[(384 + gslot)  * 4 + kq] = a3[0] + a3[1];
    parts[(512 + gslot)  * 4 + kq] = a4[0] + a4[1];
    parts[(640 + gslot)  * 4 + kq] = a5[0] + a5[1];
    if (tail) {
      f32x2 a6 = {0.f, 0.f};
      #pragma unroll
      for (int p = 0; p < 25; ++p)
        a6 += hp[p] * up2(lt[p]);
      parts[(768 + gslot - 96) * 4 + kq] = a6[0] + a6[1];
    }
    __syncthreads();

    // --- reduce + nonlinearity (threads 0..199, one wave per SIMD) ---
    if (u < 200) {
      f32x4 pI = *(const f32x4*)&parts[4 * u];
      f32x4 pF = *(const f32x4*)&parts[4 * (200 + u)];
      f32x4 pG = *(const f32x4*)&parts[4 * (400 + u)];
      f32x4 pO = *(const f32x4*)&parts[4 * (600 + u)];
      float gi = pI[0] + pI[1] + pI[2] + pI[3] + bI + bfr2f(qI);
      float gf = pF[0] + pF[1] + pF[2] + pF[3] + bF + bfr2f(qF);
      float gg = pG[0] + pG[1] + pG[2] + pG[3] + bG + bfr2f(qG);
      float go = pO[0] + pO[1] + pO[2] + pO[3] + bO + bfr2f(qO);
      float si = sigm(gi), sf = sigm(gf), so = sigm(go);
      float cn = sf * creg + si * tanh_f(gg);
      float hn = so * tanh_f(cn);
      bool kp = (mk == 0);
      creg = kp ? cn : creg;
      hreg = kp ? hn : hreg;
      hsh[u] = hreg;
      out[((size_t)row * T + t) * ostride + dir * H + u] =
          __float2bfloat16(kp ? hn : 0.0f);
    }
    __syncthreads();
  }

  if (final_h != nullptr && u < 200) {
    // glob_h = [hb1 | hf1]: backward dir -> cols 0..199, forward -> 200..399
    int col = dir ? u : (H + u);
    final_h[(size_t)row * 400 + col] = hreg;
  }
}

// ---------------------------------------------------------------------------
// Span sums
__global__ __launch_bounds__(256) void span_sum(
    const __hip_bfloat16* __restrict__ rnn,   // [B][T][400]
    const int* __restrict__ masks,
    const int* __restrict__ subj_pos,
    const int* __restrict__ obj_pos,
    float* __restrict__ obj_h,   // [B][400]
    float* __restrict__ subj_h)  // [B][400]
{
  int b = blockIdx.x;
  for (int d = threadIdx.x; d < 400; d += 256) {
    float ss = 0.f, so = 0.f;
    for (int t = 0; t < T; ++t) {
      int m = masks[b * T + t];
      float v = __bfloat162float(rnn[((size_t)b * T + t) * 400 + d]);
      if (subj_pos[b * T + t] + m == 0) ss += v;
      if (obj_pos[b * T + t] + m == 0) so += v;
    }
    subj_h[(size_t)b * 400 + d] = ss;
    obj_h[(size_t)b * 400 + d] = so;
  }
}

// ---------------------------------------------------------------------------
// Single-query attention pooling. grid = 3*128 (qi = blk>>7, b = blk&127)
__global__ __launch_bounds__(256) void attn_pool_k(
    const float* __restrict__ qbuf,           // [3][B][400]
    const __hip_bfloat16* __restrict__ rnn,   // [B][T][400]
    const int* __restrict__ masks,
    float* __restrict__ outp)                 // [3][B][400]
{
  int b = blockIdx.x & 127;
  int qi = blockIdx.x >> 7;
  __shared__ float qs[400];
  __shared__ float ps[256];
  __shared__ float red[256];
  const float* q = qbuf + ((size_t)qi * B + b) * 400;
  for (int d = threadIdx.x; d < 400; d += 256) qs[d] = q[d];
  __syncthreads();

  int t = threadIdx.x;
  const __hip_bfloat16* kv = rnn + ((size_t)b * T + t) * 400;
  float s = 0.f;
  for (int d = 0; d < 400; ++d) s += qs[d] * __bfloat162float(kv[d]);
  s *= 0.05f;  // 1/sqrt(400)
  if (masks[b * T + t] != 0) s = -1e9f;

  red[t] = s;
  __syncthreads();
  for (int off = 128; off > 0; off >>= 1) {
    if (t < off) red[t] = fmaxf(red[t], red[t + off]);
    __syncthreads();
  }
  float mx = red[0];
  __syncthreads();
  float e = expf(s - mx);
  red[t] = e;
  __syncthreads();
  for (int off = 128; off > 0; off >>= 1) {
    if (t < off) red[t] += red[t + off];
    __syncthreads();
  }
  float inv = 1.0f / red[0];
  ps[t] = e * inv;
  __syncthreads();

  for (int d = threadIdx.x; d < 400; d += 256) {
    float acc = 0.f;
    for (int t2 = 0; t2 < T; ++t2)
      acc += ps[t2] * __bfloat162float(rnn[((size_t)b * T + t2) * 400 + d]);
    outp[((size_t)qi * B + b) * 400 + d] = acc;
  }
}

// ---------------------------------------------------------------------------
// Head
__global__ __launch_bounds__(256) void final_head(
    const float* __restrict__ attn,   // [3][B][400]: 0=obj,1=subj,2=glob
    const __hip_bfloat16* __restrict__ wo_w, const __hip_bfloat16* __restrict__ wo_b,
    const __hip_bfloat16* __restrict__ ws_w, const __hip_bfloat16* __restrict__ ws_b,
    const __hip_bfloat16* __restrict__ wg_w, const __hip_bfloat16* __restrict__ wg_b,
    const __hip_bfloat16* __restrict__ cls_w, const __hip_bfloat16* __restrict__ cls_b,
    void* __restrict__ outp,          // [B][2]
    const int* __restrict__ flag)
{
  int b = blockIdx.x;
  __shared__ float hs[H];
  int j = threadIdx.x;
  if (j < H) {
    float acc = __bfloat162float(wo_b[j]) + __bfloat162float(ws_b[j]) +
                __bfloat162float(wg_b[j]);
    const float* oa = attn + ((size_t)0 * B + b) * 400;
    const float* sa = attn + ((size_t)1 * B + b) * 400;
    const float* ga = attn + ((size_t)2 * B + b) * 400;
    for (int d = 0; d < 400; ++d) {
      acc += oa[d] * __bfloat162float(wo_w[(size_t)j * 400 + d]);
      acc += sa[d] * __bfloat162float(ws_w[(size_t)j * 400 + d]);
      acc += ga[d] * __bfloat162float(wg_w[(size_t)j * 400 + d]);
    }
    hs[j] = fmaxf(acc, 0.0f);
  }
  __syncthreads();
  if (j < 2) {
    float a = __bfloat162float(cls_b[j]);
    for (int k = 0; k < H; ++k)
      a += hs[k] * __bfloat162float(cls_w[(size_t)j * H + k]);
    if (*flag) ((float*)outp)[b * 2 + j] = a;
    else       ((__hip_bfloat16*)outp)[b * 2 + j] = __float2bfloat16(a);
  }
}

// ---------------------------------------------------------------------------
// Workspace layout (bytes)
constexpr size_t O_X0   = 0;            // 32768*384*2  = 25165824
constexpr size_t O_X1   = 25165824;     // 32768*416*2  = 27262976
constexpr size_t O_GPRE = 52428800;     // 2*32768*800*2 = 104857600 (embC overlaid pre-GEMM)
constexpr size_t O_RNN  = 157286400;    // 32768*400*2  = 26214400
constexpr size_t O_WIH0 = 183500800;    // 2*800*384*2  = 1228800
constexpr size_t O_WIH1 = 184729600;    // 2*800*416*2  = 1331200
constexpr size_t O_WPK  = 186060800;    // 4*800*100*4  = 1280000
constexpr size_t O_Q    = 187340800;    // 3*128*400*4  = 614400
constexpr size_t O_ATT  = 187955200;    // 614400
constexpr size_t O_FLAG = 188569600;    // 256
constexpr size_t O_POSC = 188569856;
constexpr size_t O_NERC = 188572864;
constexpr size_t O_BIAS = 188574368;    // 4*800*2 = 6400
constexpr size_t O_WOW  = 188580768;    // 80000*2 = 160000
constexpr size_t O_WSW  = 188740768;
constexpr size_t O_WGW  = 188900768;
constexpr size_t O_WOB  = 189060768;
constexpr size_t O_WSB  = 189061168;
constexpr size_t O_WGB  = 189061568;
constexpr size_t O_CLSW = 189061968;
constexpr size_t O_CLSB = 189062768;

extern "C" void kernel_launch(void* const* d_in, const int* in_sizes, int n_in,
                              void* d_out, int out_size, void* d_ws, size_t ws_size,
                              hipStream_t stream) {
  (void)in_sizes; (void)n_in; (void)out_size; (void)ws_size;

  const int* words = (const int*)d_in[0];
  const int* masks = (const int*)d_in[1];
  const int* pos   = (const int*)d_in[2];
  const int* ner   = (const int*)d_in[3];
  const int* subj  = (const int*)d_in[4];
  const int* obj   = (const int*)d_in[5];
  const void* emb_w = d_in[6];
  const void* pos_w = d_in[7];
  const void* ner_w = d_in[8];
  const void* wih[4]  = {d_in[9],  d_in[12], d_in[15], d_in[18]};
  const void* whh[4]  = {d_in[10], d_in[13], d_in[16], d_in[19]};
  const void* bias[4] = {d_in[11], d_in[14], d_in[17], d_in[20]};
  const void* wo_w = d_in[21]; const void* wo_b = d_in[22];
  const void* ws_w = d_in[23]; const void* ws_b = d_in[24];
  const void* wg_w = d_in[25]; const void* wg_b = d_in[26];
  const void* cls_w = d_in[27]; const void* cls_b = d_in[28];

  char* ws = (char*)d_ws;
  __hip_bfloat16* X0   = (__hip_bfloat16*)(ws + O_X0);
  __hip_bfloat16* X1   = (__hip_bfloat16*)(ws + O_X1);
  __hip_bfloat16* Gpre = (__hip_bfloat16*)(ws + O_GPRE);
  __hip_bfloat16* embC = (__hip_bfloat16*)(ws + O_GPRE);  // overlaid (dead before GEMM)
  __hip_bfloat16* RNN  = (__hip_bfloat16*)(ws + O_RNN);
  __hip_bfloat16* wih0p = (__hip_bfloat16*)(ws + O_WIH0);  // [2][800][384]
  __hip_bfloat16* wih1p = (__hip_bfloat16*)(ws + O_WIH1);  // [2][800][416]
  unsigned* Wpack = (unsigned*)(ws + O_WPK);               // [4][800][100]
  float* qbuf = (float*)(ws + O_Q);    // [3][B][400]: obj, subj, glob
  float* attb = (float*)(ws + O_ATT);  // [3][B][400]
  int* flag = (int*)(ws + O_FLAG);
  __hip_bfloat16* posC = (__hip_bfloat16*)(ws + O_POSC);
  __hip_bfloat16* nerC = (__hip_bfloat16*)(ws + O_NERC);
  __hip_bfloat16* biasC = (__hip_bfloat16*)(ws + O_BIAS);  // [4][800]
  __hip_bfloat16* woW = (__hip_bfloat16*)(ws + O_WOW);
  __hip_bfloat16* wsW = (__hip_bfloat16*)(ws + O_WSW);
  __hip_bfloat16* wgW = (__hip_bfloat16*)(ws + O_WGW);
  __hip_bfloat16* woB = (__hip_bfloat16*)(ws + O_WOB);
  __hip_bfloat16* wsB = (__hip_bfloat16*)(ws + O_WSB);
  __hip_bfloat16* wgB = (__hip_bfloat16*)(ws + O_WGB);
  __hip_bfloat16* clsW = (__hip_bfloat16*)(ws + O_CLSW);
  __hip_bfloat16* clsB = (__hip_bfloat16*)(ws + O_CLSB);

  // --- dtype detect + conversions ---
  detect_dtype<<<1, 256, 0, stream>>>((const unsigned short*)emb_w, flag);
  conv_to_bf16<<<1024, 256, 0, stream>>>(emb_w, embC, 40000 * 300, flag);
  conv_to_bf16<<<2, 256, 0, stream>>>(pos_w, posC, 50 * 30, flag);
  conv_to_bf16<<<1, 256, 0, stream>>>(ner_w, nerC, 25 * 30, flag);
  for (int i = 0; i < 4; ++i)
    conv_to_bf16<<<2, 256, 0, stream>>>(bias[i], biasC + i * G4, G4, flag);
  conv_to_bf16<<<64, 256, 0, stream>>>(wo_w, woW, H * 400, flag);
  conv_to_bf16<<<64, 256, 0, stream>>>(ws_w, wsW, H * 400, flag);
  conv_to_bf16<<<64, 256, 0, stream>>>(wg_w, wgW, H * 400, flag);
  conv_to_bf16<<<1, 256, 0, stream>>>(wo_b, woB, H, flag);
  conv_to_bf16<<<1, 256, 0, stream>>>(ws_b, wsB, H, flag);
  conv_to_bf16<<<1, 256, 0, stream>>>(wg_b, wgB, H, flag);
  conv_to_bf16<<<1, 256, 0, stream>>>(cls_w, clsW, 2 * H, flag);
  conv_to_bf16<<<1, 256, 0, stream>>>(cls_b, clsB, 2, flag);

  // --- weight prep ---
  pad_copy<<<G4, 128, 0, stream>>>(wih[0], wih0p,               K0, K0P, flag);
  pad_copy<<<G4, 128, 0, stream>>>(wih[1], wih0p + G4 * K0P,    K0, K0P, flag);
  pad_copy<<<G4, 128, 0, stream>>>(wih[2], wih1p,               K1, K1P, flag);
  pad_copy<<<G4, 128, 0, stream>>>(wih[3], wih1p + G4 * K1P,    K1, K1P, flag);
  for (int i = 0; i < 4; ++i)
    pack_whh<<<313, 256, 0, stream>>>(whh[i], Wpack + (size_t)i * G4 * 100, flag);

  // --- embedding + X1 pad ---
  embed_kernel<<<BT, 128, 0, stream>>>(words, pos, ner, embC, posC, nerC, X0);
  zero_x1_tail<<<2048, 256, 0, stream>>>(X1);

  dim3 ggrid(BT / 64, 13);

  // --- layer 0: input projections + recurrence ---
  gemm_bt<<<ggrid, 256, 0, stream>>>(X0, wih0p,            Gpre,                   G4, K0P);
  gemm_bt<<<ggrid, 256, 0, stream>>>(X0, wih0p + G4 * K0P, Gpre + (size_t)BT * G4, G4, K0P);
  lstm_row<<<256, 512, 0, stream>>>(Gpre, Wpack, biasC, biasC + G4, masks,
                                    X1, K1P, nullptr);

  // --- layer 1 ---
  gemm_bt<<<ggrid, 256, 0, stream>>>(X1, wih1p,            Gpre,                   G4, K1P);
  gemm_bt<<<ggrid, 256, 0, stream>>>(X1, wih1p + G4 * K1P, Gpre + (size_t)BT * G4, G4, K1P);
  float* qglob = qbuf + (size_t)2 * B * 400;
  lstm_row<<<256, 512, 0, stream>>>(Gpre, Wpack + (size_t)2 * G4 * 100,
                                    biasC + 2 * G4, biasC + 3 * G4, masks,
                                    RNN, 400, qglob);

  // --- span sums (obj -> slot0, subj -> slot1) ---
  span_sum<<<B, 256, 0, stream>>>(RNN, masks, subj, obj,
                                  qbuf, qbuf + (size_t)B * 400);

  // --- attention pooling (3 queries) ---
  attn_pool_k<<<3 * B, 256, 0, stream>>>(qbuf, RNN, masks, attb);

  // --- head ---
  final_head<<<B, 256, 0, stream>>>(attb, woW, woB, wsW, wsB, wgW, wgB,
                                    clsW, clsB, d_out, flag);
}

// Round 9
// 2207.243 us; speedup vs baseline: 3.2896x; 3.2896x over previous
//
#include <hip/hip_runtime.h>
#include <hip/hip_bf16.h>
#include <math.h>

// Problem constants
constexpr int B = 128;
constexpr int T = 256;
constexpr int H = 200;       // hidden
constexpr int G4 = 800;      // 4*H
constexpr int BT = B * T;    // 32768
constexpr int K0 = 360, K0P = 384;   // layer0 input dim, padded to %32
constexpr int K1 = 400, K1P = 416;   // layer1 input dim, padded to %32

typedef __bf16 bf16x8 __attribute__((ext_vector_type(8)));
typedef float f32x4 __attribute__((ext_vector_type(4)));
typedef float f32x2 __attribute__((ext_vector_type(2)));
typedef _Float16 half2v __attribute__((ext_vector_type(2)));

__device__ __forceinline__ float bfr2f(unsigned short u) {
  union { unsigned int i; float f; } x;
  x.i = ((unsigned int)u) << 16;
  return x.f;
}
__device__ __forceinline__ unsigned short f2bu(float f) {
  __hip_bfloat16 b = __float2bfloat16(f);
  return *(unsigned short*)&b;
}
__device__ __forceinline__ unsigned short f2hu(float f) {
  _Float16 h = (_Float16)f;
  return *(unsigned short*)&h;
}
__device__ __forceinline__ half2v ash2(unsigned u) {
  union { unsigned v; half2v h; } x;
  x.v = u;
  return x.h;
}
__device__ __forceinline__ float sigm(float x) {
  return 1.0f / (1.0f + __expf(-x));
}
__device__ __forceinline__ float tanh_f(float x) {
  float e = __expf(2.0f * x);
  return (e - 1.0f) / (e + 1.0f);
}

// ---------------------------------------------------------------------------
// Dtype detector (f32 vs bf16 storage of float inputs); see round-2 notes.
__global__ void detect_dtype(const unsigned short* __restrict__ raw,
                             int* __restrict__ flag) {
  __shared__ int cnt[256];
  int c = 0;
  for (int j = 0; j < 32; ++j) {
    unsigned short u = raw[1024 + threadIdx.x * 32 + j];
    int e = (u >> 7) & 0xFF;
    if (e >= 0xC0) ++c;
  }
  cnt[threadIdx.x] = c;
  __syncthreads();
  for (int off = 128; off > 0; off >>= 1) {
    if (threadIdx.x < off) cnt[threadIdx.x] += cnt[threadIdx.x + off];
    __syncthreads();
  }
  if (threadIdx.x == 0) *flag = (cnt[0] > 16) ? 1 : 0;
}

// Generic convert-to-bf16 (f32 world) or raw copy (bf16 world)
__global__ void conv_to_bf16(const void* __restrict__ src,
                             __hip_bfloat16* __restrict__ dst, int n,
                             const int* __restrict__ flag) {
  int f = *flag;
  int stride = gridDim.x * blockDim.x;
  for (int i = blockIdx.x * blockDim.x + threadIdx.x; i < n; i += stride) {
    if (f) dst[i] = __float2bfloat16(((const float*)src)[i]);
    else   ((unsigned short*)dst)[i] = ((const unsigned short*)src)[i];
  }
}

// ---------------------------------------------------------------------------
// Embedding concat into X0 [BT][K0P]
__global__ void embed_kernel(const int* __restrict__ words,
                             const int* __restrict__ pos,
                             const int* __restrict__ ner,
                             const __hip_bfloat16* __restrict__ embC,
                             const __hip_bfloat16* __restrict__ posC,
                             const __hip_bfloat16* __restrict__ nerC,
                             __hip_bfloat16* __restrict__ X0) {
  int bt = blockIdx.x;
  int w = words[bt], p = pos[bt], nr = ner[bt];
  for (int j = threadIdx.x; j < K0P; j += blockDim.x) {
    __hip_bfloat16 v;
    if (j < 300)       v = embC[(size_t)w * 300 + j];
    else if (j < 330)  v = posC[(size_t)p * 30 + (j - 300)];
    else if (j < 360)  v = nerC[(size_t)nr * 30 + (j - 330)];
    else               v = __float2bfloat16(0.0f);
    X0[(size_t)bt * K0P + j] = v;
  }
}

// Zero the K-pad tail columns [400:416) of X1
__global__ void zero_x1_tail(__hip_bfloat16* __restrict__ X1) {
  int idx = blockIdx.x * blockDim.x + threadIdx.x;  // BT*16 threads
  int bt = idx >> 4, j = idx & 15;
  X1[(size_t)bt * K1P + 400 + j] = __float2bfloat16(0.0f);
}

// Pad-copy a weight matrix [rows,K] -> [rows,Kp] with zero fill (+dtype conv)
__global__ void pad_copy(const void* __restrict__ src,
                         __hip_bfloat16* __restrict__ dst, int K, int Kp,
                         const int* __restrict__ flag) {
  int r = blockIdx.x;
  int f = *flag;
  for (int j = threadIdx.x; j < Kp; j += blockDim.x) {
    __hip_bfloat16 v = __float2bfloat16(0.0f);
    if (j < K)
      v = f ? __float2bfloat16(((const float*)src)[(size_t)r * K + j])
            : ((const __hip_bfloat16*)src)[(size_t)r * K + j];
    dst[(size_t)r * Kp + j] = v;
  }
}

// Pack W_hh [800][200] into k-pairwise FP16 dwords:
// Wpack[n][p] = fp16(w[n][2p]) | fp16(w[n][2p+1])<<16.
// fp16 is exact for these weights (bf16 7-bit mantissa subset of fp16 10-bit,
// |w|~0.3 max well inside fp16 range); enables v_dot2_f32_f16 in the
// recurrence (1 instr / 2 MACs vs 3 for unpack+pk_fma).
__global__ void pack_whh(const void* __restrict__ src,
                         unsigned* __restrict__ dst,
                         const int* __restrict__ flag) {
  int idx = blockIdx.x * blockDim.x + threadIdx.x;  // 800*100
  if (idx >= G4 * 100) return;
  int f = *flag;
  int n = idx / 100, p = idx % 100;
  float lo_f, hi_f;
  if (f) {
    lo_f = ((const float*)src)[(size_t)n * 200 + 2 * p];
    hi_f = ((const float*)src)[(size_t)n * 200 + 2 * p + 1];
  } else {
    lo_f = bfr2f(((const unsigned short*)src)[(size_t)n * 200 + 2 * p]);
    hi_f = bfr2f(((const unsigned short*)src)[(size_t)n * 200 + 2 * p + 1]);
  }
  dst[idx] = (unsigned)f2hu(lo_f) | ((unsigned)f2hu(hi_f) << 16);
}

// ---------------------------------------------------------------------------
// MFMA GEMM: C[M,800] = A[M,Kp] @ Bm[800,Kp]^T   (bf16 in, fp32 acc, bf16 out)
__global__ __launch_bounds__(256) void gemm_bt(
    const __hip_bfloat16* __restrict__ A,
    const __hip_bfloat16* __restrict__ Bm,
    __hip_bfloat16* __restrict__ C,
    int N, int Kp) {
  const int lane = threadIdx.x & 63;
  const int wave = threadIdx.x >> 6;
  const int l15 = lane & 15, quad = lane >> 4;
  const int m0 = blockIdx.x * 64 + (wave & 1) * 32;
  const int n0 = blockIdx.y * 64 + (wave >> 1) * 32;

  f32x4 acc[2][2] = {};

  int c0 = n0 + l15;       if (c0 > N - 1) c0 = N - 1;
  int c1 = n0 + 16 + l15;  if (c1 > N - 1) c1 = N - 1;
  const size_t ar0 = (size_t)(m0 + l15) * Kp;
  const size_t ar1 = (size_t)(m0 + 16 + l15) * Kp;
  const size_t br0 = (size_t)c0 * Kp;
  const size_t br1 = (size_t)c1 * Kp;

  for (int k0 = 0; k0 < Kp; k0 += 32) {
    int ko = k0 + quad * 8;
    bf16x8 a0 = *(const bf16x8*)(A + ar0 + ko);
    bf16x8 a1 = *(const bf16x8*)(A + ar1 + ko);
    bf16x8 b0 = *(const bf16x8*)(Bm + br0 + ko);
    bf16x8 b1 = *(const bf16x8*)(Bm + br1 + ko);
    acc[0][0] = __builtin_amdgcn_mfma_f32_16x16x32_bf16(a0, b0, acc[0][0], 0, 0, 0);
    acc[0][1] = __builtin_amdgcn_mfma_f32_16x16x32_bf16(a0, b1, acc[0][1], 0, 0, 0);
    acc[1][0] = __builtin_amdgcn_mfma_f32_16x16x32_bf16(a1, b0, acc[1][0], 0, 0, 0);
    acc[1][1] = __builtin_amdgcn_mfma_f32_16x16x32_bf16(a1, b1, acc[1][1], 0, 0, 0);
  }
  #pragma unroll
  for (int mi = 0; mi < 2; ++mi)
    #pragma unroll
    for (int ni = 0; ni < 2; ++ni)
      #pragma unroll
      for (int r = 0; r < 4; ++r) {
        int row = m0 + mi * 16 + quad * 4 + r;
        int col = n0 + ni * 16 + l15;
        if (col < N)
          C[(size_t)row * N + col] = __float2bfloat16(acc[mi][ni][r]);
      }
}

// ---------------------------------------------------------------------------
// LSTM recurrence v4 — round-7's verified no-spill shape (256 threads,
// >80 KB static LDS -> 1 block/CU -> 224-VGPR grant; the allocator always
// budgets for 2 blocks/CU: 256thr->224, 512thr->128, 1024thr->64 measured)
// with round-7's two measured bottlenecks fixed:
//  (1) weights+h in FP16, dot via v_dot2_f32_f16 (1 instr / 2 MACs, f32 acc)
//  (2) LDS weights transposed wldsT[p*288+g]: at fixed p lanes read
//      consecutive g -> strictly conflict-free b32 (round 7: 62M conflicts
//      from gate-major b64 reads).
// grid 256 = dir*128 + row. Thread (kh=tid&1, gs=tid>>1 in [0,128)):
//   registers: k-half kh of gates {gs+128j, j<4} = 200 dwords (400 weights)
//   LDS: gates 512..799 (288); thread handles {512+gs, 640+gs}
//        (+ 768+(gs-96) for tid>=192, wave-3-uniform).
// Partials parts[kh*804+g]; 200 reduce threads: 2 halves + bias + Gpre,
// nonlinearity (c,h in f32; h stored to LDS as fp16 for the next step's dot).
__global__ __launch_bounds__(256, 1) void lstm_row(
    const __hip_bfloat16* __restrict__ Gpre,   // [2][B*T][800]  x@W_ih^T (no bias)
    const unsigned* __restrict__ Wpack,        // [2][800][100] packed fp16 k-pairs
    const __hip_bfloat16* __restrict__ bias_f, // [800]
    const __hip_bfloat16* __restrict__ bias_b, // [800]
    const int* __restrict__ masks,             // [B][T], 1 = pad
    __hip_bfloat16* __restrict__ out,          // [B][T][ostride], cols dir*200..+200
    int ostride,
    float* __restrict__ final_h)               // [B][400] = [hb | hf], or nullptr
{
  const int tid = threadIdx.x;
  const int dir = blockIdx.x >> 7;
  const int row = blockIdx.x & 127;
  const int kh = tid & 1;            // k-half: k-pairs [kh*50, kh*50+50)
  const int gs = tid >> 1;           // 0..127
  const bool tail = (tid >= 192);    // wave 3 (gs in [96,128)) — wave-uniform

  __shared__ __align__(16) _Float16 hsh[200];     // h state, fp16
  __shared__ float parts[2 * 804];                // [kh][gate(+4)], 6432 B
  __shared__ int msk[T];                          // 1024 B
  __shared__ unsigned wldsT[100 * 288];           // [p][gate-512], 115200 B

  const unsigned* wb = Wpack + (size_t)dir * G4 * 100;

  // --- stage LDS weights, transposed (one-time) ---
  for (int i = tid; i < 28800; i += 256) {
    int p = i / 288, g = i - p * 288;
    wldsT[i] = wb[(512 + g) * 100 + p];
  }
  // --- mask row preload ---
  for (int i = tid; i < T; i += 256) msk[i] = masks[row * T + i];

  // --- register weights: 200 dwords/thread, compile-time indices ---
  unsigned w[4][50];
  {
    const unsigned* s = wb + gs * 100 + kh * 50;
    #pragma unroll
    for (int j = 0; j < 4; ++j)
      #pragma unroll
      for (int p = 0; p < 50; ++p)
        w[j][p] = s[12800 * j + p];
  }

  // --- reduce-thread constants (u = hidden unit) ---
  const int u = tid;
  const __hip_bfloat16* bias = dir ? bias_b : bias_f;
  float bI = 0.f, bF = 0.f, bG = 0.f, bO = 0.f;
  if (u < 200) {
    bI = __bfloat162float(bias[u]);
    bF = __bfloat162float(bias[200 + u]);
    bG = __bfloat162float(bias[400 + u]);
    bO = __bfloat162float(bias[600 + u]);
  }

  if (tid < 200) hsh[tid] = (_Float16)0.0f;
  float creg = 0.0f, hreg = 0.0f;
  __syncthreads();

  const unsigned short* gp = (const unsigned short*)Gpre + (size_t)dir * BT * G4;
  const size_t gbase = (size_t)row * T * G4;
  const half2v* hp = (const half2v*)hsh + kh * 50;
  const unsigned* lb = wldsT + kh * 50 * 288;   // this k-half's p-plane base
  const int g0 = gs, g1 = 128 + gs, g2 = 160 + gs;  // g2: 256+(gs-96)

  #pragma unroll 1
  for (int tt = 0; tt < T; ++tt) {
    const int t = dir ? (T - 1 - tt) : tt;
    const size_t goff = gbase + (size_t)t * G4;
    // prefetch gate pre-activations + mask (consumed in the reduce phase)
    unsigned short qI = 0, qF = 0, qG = 0, qO = 0;
    int mk = 0;
    if (u < 200) {
      qI = gp[goff + u];
      qF = gp[goff + 200 + u];
      qG = gp[goff + 400 + u];
      qO = gp[goff + 600 + u];
      mk = msk[t];
    }

    // --- dot phase: fp16 dot2, f32 accumulate ---
    float a0 = 0.f, a1 = 0.f, a2 = 0.f, a3 = 0.f, a4 = 0.f, a5 = 0.f;
    #pragma unroll
    for (int p = 0; p < 50; ++p) {
      half2v h2 = hp[p];
      a0 = __builtin_amdgcn_fdot2(ash2(w[0][p]), h2, a0, false);
      a1 = __builtin_amdgcn_fdot2(ash2(w[1][p]), h2, a1, false);
      a2 = __builtin_amdgcn_fdot2(ash2(w[2][p]), h2, a2, false);
      a3 = __builtin_amdgcn_fdot2(ash2(w[3][p]), h2, a3, false);
      a4 = __builtin_amdgcn_fdot2(ash2(lb[p * 288 + g0]), h2, a4, false);
      a5 = __builtin_amdgcn_fdot2(ash2(lb[p * 288 + g1]), h2, a5, false);
    }
    const int pb = kh * 804;
    parts[pb + gs]        = a0;
    parts[pb + 128 + gs]  = a1;
    parts[pb + 256 + gs]  = a2;
    parts[pb + 384 + gs]  = a3;
    parts[pb + 512 + gs]  = a4;
    parts[pb + 640 + gs]  = a5;
    if (tail) {
      float a6 = 0.f;
      #pragma unroll
      for (int p = 0; p < 50; ++p)
        a6 = __builtin_amdgcn_fdot2(ash2(lb[p * 288 + g2]), hp[p], a6, false);
      parts[pb + 672 + gs] = a6;   // gate 768+(gs-96) = 672+gs
    }
    __syncthreads();

    // --- reduce + nonlinearity (threads 0..199) ---
    if (u < 200) {
      float gi = parts[u]       + parts[804 + u]       + bI + bfr2f(qI);
      float gf = parts[200 + u] + parts[804 + 200 + u] + bF + bfr2f(qF);
      float gg = parts[400 + u] + parts[804 + 400 + u] + bG + bfr2f(qG);
      float go = parts[600 + u] + parts[804 + 600 + u] + bO + bfr2f(qO);
      float si = sigm(gi), sf = sigm(gf), so = sigm(go);
      float cn = sf * creg + si * tanh_f(gg);
      float hn = so * tanh_f(cn);
      bool kp = (mk == 0);
      creg = kp ? cn : creg;
      hreg = kp ? hn : hreg;
      hsh[u] = (_Float16)hreg;
      out[((size_t)row * T + t) * ostride + dir * H + u] =
          __float2bfloat16(kp ? hn : 0.0f);
    }
    __syncthreads();
  }

  if (final_h != nullptr && u < 200) {
    // glob_h = [hb1 | hf1]: backward dir -> cols 0..199, forward -> 200..399
    int col = dir ? u : (H + u);
    final_h[(size_t)row * 400 + col] = hreg;
  }
}

// ---------------------------------------------------------------------------
// Span sums
__global__ __launch_bounds__(256) void span_sum(
    const __hip_bfloat16* __restrict__ rnn,   // [B][T][400]
    const int* __restrict__ masks,
    const int* __restrict__ subj_pos,
    const int* __restrict__ obj_pos,
    float* __restrict__ obj_h,   // [B][400]
    float* __restrict__ subj_h)  // [B][400]
{
  int b = blockIdx.x;
  for (int d = threadIdx.x; d < 400; d += 256) {
    float ss = 0.f, so = 0.f;
    for (int t = 0; t < T; ++t) {
      int m = masks[b * T + t];
      float v = __bfloat162float(rnn[((size_t)b * T + t) * 400 + d]);
      if (subj_pos[b * T + t] + m == 0) ss += v;
      if (obj_pos[b * T + t] + m == 0) so += v;
    }
    subj_h[(size_t)b * 400 + d] = ss;
    obj_h[(size_t)b * 400 + d] = so;
  }
}

// ---------------------------------------------------------------------------
// Single-query attention pooling. grid = 3*128 (qi = blk>>7, b = blk&127)
__global__ __launch_bounds__(256) void attn_pool_k(
    const float* __restrict__ qbuf,           // [3][B][400]
    const __hip_bfloat16* __restrict__ rnn,   // [B][T][400]
    const int* __restrict__ masks,
    float* __restrict__ outp)                 // [3][B][400]
{
  int b = blockIdx.x & 127;
  int qi = blockIdx.x >> 7;
  __shared__ float qs[400];
  __shared__ float ps[256];
  __shared__ float red[256];
  const float* q = qbuf + ((size_t)qi * B + b) * 400;
  for (int d = threadIdx.x; d < 400; d += 256) qs[d] = q[d];
  __syncthreads();

  int t = threadIdx.x;
  const __hip_bfloat16* kv = rnn + ((size_t)b * T + t) * 400;
  float s = 0.f;
  for (int d = 0; d < 400; ++d) s += qs[d] * __bfloat162float(kv[d]);
  s *= 0.05f;  // 1/sqrt(400)
  if (masks[b * T + t] != 0) s = -1e9f;

  red[t] = s;
  __syncthreads();
  for (int off = 128; off > 0; off >>= 1) {
    if (t < off) red[t] = fmaxf(red[t], red[t + off]);
    __syncthreads();
  }
  float mx = red[0];
  __syncthreads();
  float e = expf(s - mx);
  red[t] = e;
  __syncthreads();
  for (int off = 128; off > 0; off >>= 1) {
    if (t < off) red[t] += red[t + off];
    __syncthreads();
  }
  float inv = 1.0f / red[0];
  ps[t] = e * inv;
  __syncthreads();

  for (int d = threadIdx.x; d < 400; d += 256) {
    float acc = 0.f;
    for (int t2 = 0; t2 < T; ++t2)
      acc += ps[t2] * __bfloat162float(rnn[((size_t)b * T + t2) * 400 + d]);
    outp[((size_t)qi * B + b) * 400 + d] = acc;
  }
}

// ---------------------------------------------------------------------------
// Head
__global__ __launch_bounds__(256) void final_head(
    const float* __restrict__ attn,   // [3][B][400]: 0=obj,1=subj,2=glob
    const __hip_bfloat16* __restrict__ wo_w, const __hip_bfloat16* __restrict__ wo_b,
    const __hip_bfloat16* __restrict__ ws_w, const __hip_bfloat16* __restrict__ ws_b,
    const __hip_bfloat16* __restrict__ wg_w, const __hip_bfloat16* __restrict__ wg_b,
    const __hip_bfloat16* __restrict__ cls_w, const __hip_bfloat16* __restrict__ cls_b,
    void* __restrict__ outp,          // [B][2]
    const int* __restrict__ flag)
{
  int b = blockIdx.x;
  __shared__ float hs[H];
  int j = threadIdx.x;
  if (j < H) {
    float acc = __bfloat162float(wo_b[j]) + __bfloat162float(ws_b[j]) +
                __bfloat162float(wg_b[j]);
    const float* oa = attn + ((size_t)0 * B + b) * 400;
    const float* sa = attn + ((size_t)1 * B + b) * 400;
    const float* ga = attn + ((size_t)2 * B + b) * 400;
    for (int d = 0; d < 400; ++d) {
      acc += oa[d] * __bfloat162float(wo_w[(size_t)j * 400 + d]);
      acc += sa[d] * __bfloat162float(ws_w[(size_t)j * 400 + d]);
      acc += ga[d] * __bfloat162float(wg_w[(size_t)j * 400 + d]);
    }
    hs[j] = fmaxf(acc, 0.0f);
  }
  __syncthreads();
  if (j < 2) {
    float a = __bfloat162float(cls_b[j]);
    for (int k = 0; k < H; ++k)
      a += hs[k] * __bfloat162float(cls_w[(size_t)j * H + k]);
    if (*flag) ((float*)outp)[b * 2 + j] = a;
    else       ((__hip_bfloat16*)outp)[b * 2 + j] = __float2bfloat16(a);
  }
}

// ---------------------------------------------------------------------------
// Workspace layout (bytes)
constexpr size_t O_X0   = 0;            // 32768*384*2  = 25165824
constexpr size_t O_X1   = 25165824;     // 32768*416*2  = 27262976
constexpr size_t O_GPRE = 52428800;     // 2*32768*800*2 = 104857600 (embC overlaid pre-GEMM)
constexpr size_t O_RNN  = 157286400;    // 32768*400*2  = 26214400
constexpr size_t O_WIH0 = 183500800;    // 2*800*384*2  = 1228800
constexpr size_t O_WIH1 = 184729600;    // 2*800*416*2  = 1331200
constexpr size_t O_WPK  = 186060800;    // 4*800*100*4  = 1280000
constexpr size_t O_Q    = 187340800;    // 3*128*400*4  = 614400
constexpr size_t O_ATT  = 187955200;    // 614400
constexpr size_t O_FLAG = 188569600;    // 256
constexpr size_t O_POSC = 188569856;
constexpr size_t O_NERC = 188572864;
constexpr size_t O_BIAS = 188574368;    // 4*800*2 = 6400
constexpr size_t O_WOW  = 188580768;    // 80000*2 = 160000
constexpr size_t O_WSW  = 188740768;
constexpr size_t O_WGW  = 188900768;
constexpr size_t O_WOB  = 189060768;
constexpr size_t O_WSB  = 189061168;
constexpr size_t O_WGB  = 189061568;
constexpr size_t O_CLSW = 189061968;
constexpr size_t O_CLSB = 189062768;

extern "C" void kernel_launch(void* const* d_in, const int* in_sizes, int n_in,
                              void* d_out, int out_size, void* d_ws, size_t ws_size,
                              hipStream_t stream) {
  (void)in_sizes; (void)n_in; (void)out_size; (void)ws_size;

  const int* words = (const int*)d_in[0];
  const int* masks = (const int*)d_in[1];
  const int* pos   = (const int*)d_in[2];
  const int* ner   = (const int*)d_in[3];
  const int* subj  = (const int*)d_in[4];
  const int* obj   = (const int*)d_in[5];
  const void* emb_w = d_in[6];
  const void* pos_w = d_in[7];
  const void* ner_w = d_in[8];
  const void* wih[4]  = {d_in[9],  d_in[12], d_in[15], d_in[18]};
  const void* whh[4]  = {d_in[10], d_in[13], d_in[16], d_in[19]};
  const void* bias[4] = {d_in[11], d_in[14], d_in[17], d_in[20]};
  const void* wo_w = d_in[21]; const void* wo_b = d_in[22];
  const void* ws_w = d_in[23]; const void* ws_b = d_in[24];
  const void* wg_w = d_in[25]; const void* wg_b = d_in[26];
  const void* cls_w = d_in[27]; const void* cls_b = d_in[28];

  char* ws = (char*)d_ws;
  __hip_bfloat16* X0   = (__hip_bfloat16*)(ws + O_X0);
  __hip_bfloat16* X1   = (__hip_bfloat16*)(ws + O_X1);
  __hip_bfloat16* Gpre = (__hip_bfloat16*)(ws + O_GPRE);
  __hip_bfloat16* embC = (__hip_bfloat16*)(ws + O_GPRE);  // overlaid (dead before GEMM)
  __hip_bfloat16* RNN  = (__hip_bfloat16*)(ws + O_RNN);
  __hip_bfloat16* wih0p = (__hip_bfloat16*)(ws + O_WIH0);  // [2][800][384]
  __hip_bfloat16* wih1p = (__hip_bfloat16*)(ws + O_WIH1);  // [2][800][416]
  unsigned* Wpack = (unsigned*)(ws + O_WPK);               // [4][800][100] fp16 pairs
  float* qbuf = (float*)(ws + O_Q);    // [3][B][400]: obj, subj, glob
  float* attb = (float*)(ws + O_ATT);  // [3][B][400]
  int* flag = (int*)(ws + O_FLAG);
  __hip_bfloat16* posC = (__hip_bfloat16*)(ws + O_POSC);
  __hip_bfloat16* nerC = (__hip_bfloat16*)(ws + O_NERC);
  __hip_bfloat16* biasC = (__hip_bfloat16*)(ws + O_BIAS);  // [4][800]
  __hip_bfloat16* woW = (__hip_bfloat16*)(ws + O_WOW);
  __hip_bfloat16* wsW = (__hip_bfloat16*)(ws + O_WSW);
  __hip_bfloat16* wgW = (__hip_bfloat16*)(ws + O_WGW);
  __hip_bfloat16* woB = (__hip_bfloat16*)(ws + O_WOB);
  __hip_bfloat16* wsB = (__hip_bfloat16*)(ws + O_WSB);
  __hip_bfloat16* wgB = (__hip_bfloat16*)(ws + O_WGB);
  __hip_bfloat16* clsW = (__hip_bfloat16*)(ws + O_CLSW);
  __hip_bfloat16* clsB = (__hip_bfloat16*)(ws + O_CLSB);

  // --- dtype detect + conversions ---
  detect_dtype<<<1, 256, 0, stream>>>((const unsigned short*)emb_w, flag);
  conv_to_bf16<<<1024, 256, 0, stream>>>(emb_w, embC, 40000 * 300, flag);
  conv_to_bf16<<<2, 256, 0, stream>>>(pos_w, posC, 50 * 30, flag);
  conv_to_bf16<<<1, 256, 0, stream>>>(ner_w, nerC, 25 * 30, flag);
  for (int i = 0; i < 4; ++i)
    conv_to_bf16<<<2, 256, 0, stream>>>(bias[i], biasC + i * G4, G4, flag);
  conv_to_bf16<<<64, 256, 0, stream>>>(wo_w, woW, H * 400, flag);
  conv_to_bf16<<<64, 256, 0, stream>>>(ws_w, wsW, H * 400, flag);
  conv_to_bf16<<<64, 256, 0, stream>>>(wg_w, wgW, H * 400, flag);
  conv_to_bf16<<<1, 256, 0, stream>>>(wo_b, woB, H, flag);
  conv_to_bf16<<<1, 256, 0, stream>>>(ws_b, wsB, H, flag);
  conv_to_bf16<<<1, 256, 0, stream>>>(wg_b, wgB, H, flag);
  conv_to_bf16<<<1, 256, 0, stream>>>(cls_w, clsW, 2 * H, flag);
  conv_to_bf16<<<1, 256, 0, stream>>>(cls_b, clsB, 2, flag);

  // --- weight prep ---
  pad_copy<<<G4, 128, 0, stream>>>(wih[0], wih0p,               K0, K0P, flag);
  pad_copy<<<G4, 128, 0, stream>>>(wih[1], wih0p + G4 * K0P,    K0, K0P, flag);
  pad_copy<<<G4, 128, 0, stream>>>(wih[2], wih1p,               K1, K1P, flag);
  pad_copy<<<G4, 128, 0, stream>>>(wih[3], wih1p + G4 * K1P,    K1, K1P, flag);
  for (int i = 0; i < 4; ++i)
    pack_whh<<<313, 256, 0, stream>>>(whh[i], Wpack + (size_t)i * G4 * 100, flag);

  // --- embedding + X1 pad ---
  embed_kernel<<<BT, 128, 0, stream>>>(words, pos, ner, embC, posC, nerC, X0);
  zero_x1_tail<<<2048, 256, 0, stream>>>(X1);

  dim3 ggrid(BT / 64, 13);

  // --- layer 0: input projections + recurrence ---
  gemm_bt<<<ggrid, 256, 0, stream>>>(X0, wih0p,            Gpre,                   G4, K0P);
  gemm_bt<<<ggrid, 256, 0, stream>>>(X0, wih0p + G4 * K0P, Gpre + (size_t)BT * G4, G4, K0P);
  lstm_row<<<256, 256, 0, stream>>>(Gpre, Wpack, biasC, biasC + G4, masks,
                                    X1, K1P, nullptr);

  // --- layer 1 ---
  gemm_bt<<<ggrid, 256, 0, stream>>>(X1, wih1p,            Gpre,                   G4, K1P);
  gemm_bt<<<ggrid, 256, 0, stream>>>(X1, wih1p + G4 * K1P, Gpre + (size_t)BT * G4, G4, K1P);
  float* qglob = qbuf + (size_t)2 * B * 400;
  lstm_row<<<256, 256, 0, stream>>>(Gpre, Wpack + (size_t)2 * G4 * 100,
                                    biasC + 2 * G4, biasC + 3 * G4, masks,
                                    RNN, 400, qglob);

  // --- span sums (obj -> slot0, subj -> slot1) ---
  span_sum<<<B, 256, 0, stream>>>(RNN, masks, subj, obj,
                                  qbuf, qbuf + (size_t)B * 400);

  // --- attention pooling (3 queries) ---
  attn_pool_k<<<3 * B, 256, 0, stream>>>(qbuf, RNN, masks, attb);

  // --- head ---
  final_head<<<B, 256, 0, stream>>>(attb, woW, woB, wsW, wsB, wgW, wgB,
                                    clsW, clsB, d_out, flag);
}

// Round 10
// 2141.623 us; speedup vs baseline: 3.3904x; 1.0306x over previous
//
#include <hip/hip_runtime.h>
#include <hip/hip_bf16.h>
#include <math.h>

// Problem constants
constexpr int B = 128;
constexpr int T = 256;
constexpr int H = 200;       // hidden
constexpr int G4 = 800;      // 4*H
constexpr int BT = B * T;    // 32768
constexpr int K0 = 360, K0P = 384;   // layer0 input dim, padded to %32
constexpr int K1 = 400, K1P = 416;   // layer1 input dim, padded to %32

typedef __bf16 bf16x8 __attribute__((ext_vector_type(8)));
typedef float f32x4 __attribute__((ext_vector_type(4)));
typedef float f32x2 __attribute__((ext_vector_type(2)));
typedef _Float16 half2v __attribute__((ext_vector_type(2)));
typedef unsigned uix4 __attribute__((ext_vector_type(4)));

__device__ __forceinline__ float bfr2f(unsigned short u) {
  union { unsigned int i; float f; } x;
  x.i = ((unsigned int)u) << 16;
  return x.f;
}
__device__ __forceinline__ unsigned short f2bu(float f) {
  __hip_bfloat16 b = __float2bfloat16(f);
  return *(unsigned short*)&b;
}
__device__ __forceinline__ unsigned short f2hu(float f) {
  _Float16 h = (_Float16)f;
  return *(unsigned short*)&h;
}
__device__ __forceinline__ half2v ash2(unsigned u) {
  union { unsigned v; half2v h; } x;
  x.v = u;
  return x.h;
}
__device__ __forceinline__ float sigm(float x) {
  return 1.0f / (1.0f + __expf(-x));
}
__device__ __forceinline__ float tanh_f(float x) {
  float e = __expf(2.0f * x);
  return (e - 1.0f) / (e + 1.0f);
}

// ---------------------------------------------------------------------------
// Dtype detector (f32 vs bf16 storage of float inputs); see round-2 notes.
__global__ void detect_dtype(const unsigned short* __restrict__ raw,
                             int* __restrict__ flag) {
  __shared__ int cnt[256];
  int c = 0;
  for (int j = 0; j < 32; ++j) {
    unsigned short u = raw[1024 + threadIdx.x * 32 + j];
    int e = (u >> 7) & 0xFF;
    if (e >= 0xC0) ++c;
  }
  cnt[threadIdx.x] = c;
  __syncthreads();
  for (int off = 128; off > 0; off >>= 1) {
    if (threadIdx.x < off) cnt[threadIdx.x] += cnt[threadIdx.x + off];
    __syncthreads();
  }
  if (threadIdx.x == 0) *flag = (cnt[0] > 16) ? 1 : 0;
}

// Generic convert-to-bf16 (f32 world) or raw copy (bf16 world)
__global__ void conv_to_bf16(const void* __restrict__ src,
                             __hip_bfloat16* __restrict__ dst, int n,
                             const int* __restrict__ flag) {
  int f = *flag;
  int stride = gridDim.x * blockDim.x;
  for (int i = blockIdx.x * blockDim.x + threadIdx.x; i < n; i += stride) {
    if (f) dst[i] = __float2bfloat16(((const float*)src)[i]);
    else   ((unsigned short*)dst)[i] = ((const unsigned short*)src)[i];
  }
}

// ---------------------------------------------------------------------------
// Embedding concat into X0 [BT][K0P]
__global__ void embed_kernel(const int* __restrict__ words,
                             const int* __restrict__ pos,
                             const int* __restrict__ ner,
                             const __hip_bfloat16* __restrict__ embC,
                             const __hip_bfloat16* __restrict__ posC,
                             const __hip_bfloat16* __restrict__ nerC,
                             __hip_bfloat16* __restrict__ X0) {
  int bt = blockIdx.x;
  int w = words[bt], p = pos[bt], nr = ner[bt];
  for (int j = threadIdx.x; j < K0P; j += blockDim.x) {
    __hip_bfloat16 v;
    if (j < 300)       v = embC[(size_t)w * 300 + j];
    else if (j < 330)  v = posC[(size_t)p * 30 + (j - 300)];
    else if (j < 360)  v = nerC[(size_t)nr * 30 + (j - 330)];
    else               v = __float2bfloat16(0.0f);
    X0[(size_t)bt * K0P + j] = v;
  }
}

// Zero the K-pad tail columns [400:416) of X1
__global__ void zero_x1_tail(__hip_bfloat16* __restrict__ X1) {
  int idx = blockIdx.x * blockDim.x + threadIdx.x;  // BT*16 threads
  int bt = idx >> 4, j = idx & 15;
  X1[(size_t)bt * K1P + 400 + j] = __float2bfloat16(0.0f);
}

// Pad-copy a weight matrix [rows,K] -> [rows,Kp] with zero fill (+dtype conv)
__global__ void pad_copy(const void* __restrict__ src,
                         __hip_bfloat16* __restrict__ dst, int K, int Kp,
                         const int* __restrict__ flag) {
  int r = blockIdx.x;
  int f = *flag;
  for (int j = threadIdx.x; j < Kp; j += blockDim.x) {
    __hip_bfloat16 v = __float2bfloat16(0.0f);
    if (j < K)
      v = f ? __float2bfloat16(((const float*)src)[(size_t)r * K + j])
            : ((const __hip_bfloat16*)src)[(size_t)r * K + j];
    dst[(size_t)r * Kp + j] = v;
  }
}

// Pack W_hh [800][200] into k-pairwise FP16 dwords (fp16 exact for bf16-
// derived weights; enables v_dot2_f32_f16: 1 instr / 2 MACs, f32 acc).
__global__ void pack_whh(const void* __restrict__ src,
                         unsigned* __restrict__ dst,
                         const int* __restrict__ flag) {
  int idx = blockIdx.x * blockDim.x + threadIdx.x;  // 800*100
  if (idx >= G4 * 100) return;
  int f = *flag;
  int n = idx / 100, p = idx % 100;
  float lo_f, hi_f;
  if (f) {
    lo_f = ((const float*)src)[(size_t)n * 200 + 2 * p];
    hi_f = ((const float*)src)[(size_t)n * 200 + 2 * p + 1];
  } else {
    lo_f = bfr2f(((const unsigned short*)src)[(size_t)n * 200 + 2 * p]);
    hi_f = bfr2f(((const unsigned short*)src)[(size_t)n * 200 + 2 * p + 1]);
  }
  dst[idx] = (unsigned)f2hu(lo_f) | ((unsigned)f2hu(hi_f) << 16);
}

// ---------------------------------------------------------------------------
// MFMA GEMM: C[M,800] = A[M,Kp] @ Bm[800,Kp]^T   (bf16 in, fp32 acc, bf16 out)
__global__ __launch_bounds__(256) void gemm_bt(
    const __hip_bfloat16* __restrict__ A,
    const __hip_bfloat16* __restrict__ Bm,
    __hip_bfloat16* __restrict__ C,
    int N, int Kp) {
  const int lane = threadIdx.x & 63;
  const int wave = threadIdx.x >> 6;
  const int l15 = lane & 15, quad = lane >> 4;
  const int m0 = blockIdx.x * 64 + (wave & 1) * 32;
  const int n0 = blockIdx.y * 64 + (wave >> 1) * 32;

  f32x4 acc[2][2] = {};

  int c0 = n0 + l15;       if (c0 > N - 1) c0 = N - 1;
  int c1 = n0 + 16 + l15;  if (c1 > N - 1) c1 = N - 1;
  const size_t ar0 = (size_t)(m0 + l15) * Kp;
  const size_t ar1 = (size_t)(m0 + 16 + l15) * Kp;
  const size_t br0 = (size_t)c0 * Kp;
  const size_t br1 = (size_t)c1 * Kp;

  for (int k0 = 0; k0 < Kp; k0 += 32) {
    int ko = k0 + quad * 8;
    bf16x8 a0 = *(const bf16x8*)(A + ar0 + ko);
    bf16x8 a1 = *(const bf16x8*)(A + ar1 + ko);
    bf16x8 b0 = *(const bf16x8*)(Bm + br0 + ko);
    bf16x8 b1 = *(const bf16x8*)(Bm + br1 + ko);
    acc[0][0] = __builtin_amdgcn_mfma_f32_16x16x32_bf16(a0, b0, acc[0][0], 0, 0, 0);
    acc[0][1] = __builtin_amdgcn_mfma_f32_16x16x32_bf16(a0, b1, acc[0][1], 0, 0, 0);
    acc[1][0] = __builtin_amdgcn_mfma_f32_16x16x32_bf16(a1, b0, acc[1][0], 0, 0, 0);
    acc[1][1] = __builtin_amdgcn_mfma_f32_16x16x32_bf16(a1, b1, acc[1][1], 0, 0, 0);
  }
  #pragma unroll
  for (int mi = 0; mi < 2; ++mi)
    #pragma unroll
    for (int ni = 0; ni < 2; ++ni)
      #pragma unroll
      for (int r = 0; r < 4; ++r) {
        int row = m0 + mi * 16 + quad * 4 + r;
        int col = n0 + ni * 16 + l15;
        if (col < N)
          C[(size_t)row * N + col] = __float2bfloat16(acc[mi][ni][r]);
      }
}

// ---------------------------------------------------------------------------
// LSTM recurrence v5 — round-9 discovery: at 1 block/CU (forced by >80 KB
// static LDS) the UNIFIED VGPR+AGPR grant is ~512/thread (round 9: 200-dword
// array + VGPR_Count=132, zero spill -> array lived in AGPRs). So move the
// LDS-resident gates into registers:
//   thread (kh=tid&1, gs=tid>>1): 6 gates {gs+128j, j<6} x 50 k-pairs =
//   300 weight dwords in registers (gates 0..767).
// Only tail o-gates 768..799 stay in LDS (stride 101 -> 2-way max, free),
// handled by wave 3 (tid>=192, wave-uniform). h is read as 13 ds_read_b128
// broadcasts from a gap-padded fp16 hsh (plane kh at half-offset 112).
// Per-CU per-step LDS instr: ~600 (round 9, port-bound: 62M conflict cyc,
// VALUBusy 27%) -> ~160. bigbuf (86 KB, mostly pad) keeps LDS > 80 KB to
// preserve the 1-block/CU register grant.
__global__ __launch_bounds__(256, 1) void lstm_row(
    const __hip_bfloat16* __restrict__ Gpre,   // [2][B*T][800]  x@W_ih^T (no bias)
    const unsigned* __restrict__ Wpack,        // [2][800][100] packed fp16 k-pairs
    const __hip_bfloat16* __restrict__ bias_f, // [800]
    const __hip_bfloat16* __restrict__ bias_b, // [800]
    const int* __restrict__ masks,             // [B][T], 1 = pad
    __hip_bfloat16* __restrict__ out,          // [B][T][ostride], cols dir*200..+200
    int ostride,
    float* __restrict__ final_h)               // [B][400] = [hb | hf], or nullptr
{
  const int tid = threadIdx.x;
  const int dir = blockIdx.x >> 7;
  const int row = blockIdx.x & 127;
  const int kh = tid & 1;            // k-half: k-pairs [kh*50, kh*50+50)
  const int gs = tid >> 1;           // 0..127
  const bool tail = (tid >= 192);    // gs in [96,128), wave 3 — wave-uniform

  __shared__ __align__(16) _Float16 hsh[224];  // h[0..99]@0, h[100..199]@112
  __shared__ float parts[2 * 804];             // [kh][gate(+4)], 6432 B
  __shared__ int bigbuf[21504];                // 86016 B: [0:256)=mask,
                                               // [256:3488)=tail W; rest pads
                                               // LDS >80KB for the reg grant

  const unsigned* wb = Wpack + (size_t)dir * G4 * 100;

  // --- stage tail-gate weights (768..799), stride 101 (5g'+p banks, 2-way) ---
  for (int i = tid; i < 3200; i += 256) {
    int g = i / 100, c = i - g * 100;
    bigbuf[256 + g * 101 + c] = (int)wb[(768 + g) * 100 + c];
  }
  // --- mask row preload ---
  for (int i = tid; i < T; i += 256) bigbuf[i] = masks[row * T + i];

  // --- register weights: 300 dwords/thread, compile-time indices ---
  unsigned w[6][50];
  {
    const unsigned* s = wb + gs * 100 + kh * 50;
    #pragma unroll
    for (int j = 0; j < 6; ++j)
      #pragma unroll
      for (int p = 0; p < 50; ++p)
        w[j][p] = s[12800 * j + p];
  }
  const unsigned* wt = (const unsigned*)&bigbuf[256 + (gs - 96) * 101 + kh * 50];

  // --- reduce-thread constants (u = hidden unit) ---
  const int u = tid;
  const __hip_bfloat16* bias = dir ? bias_b : bias_f;
  float bI = 0.f, bF = 0.f, bG = 0.f, bO = 0.f;
  if (u < 200) {
    bI = __bfloat162float(bias[u]);
    bF = __bfloat162float(bias[200 + u]);
    bG = __bfloat162float(bias[400 + u]);
    bO = __bfloat162float(bias[600 + u]);
  }

  if (tid < 224) hsh[tid] = (_Float16)0.0f;   // zero incl. gap pads
  float creg = 0.0f, hreg = 0.0f;
  __syncthreads();

  const unsigned short* gp = (const unsigned short*)Gpre + (size_t)dir * BT * G4;
  const size_t gbase = (size_t)row * T * G4;
  const uix4* hvp = (const uix4*)(hsh + kh * 112);  // 224 B offset, 16B aligned
  const int hwrite = (u < 100) ? u : (u + 12);      // gap-padded h index

  #pragma unroll 1
  for (int tt = 0; tt < T; ++tt) {
    const int t = dir ? (T - 1 - tt) : tt;
    const size_t goff = gbase + (size_t)t * G4;
    // prefetch gate pre-activations + mask (consumed in the reduce phase)
    unsigned short qI = 0, qF = 0, qG = 0, qO = 0;
    int mk = 0;
    if (u < 200) {
      qI = gp[goff + u];
      qF = gp[goff + 200 + u];
      qG = gp[goff + 400 + u];
      qO = gp[goff + 600 + u];
      mk = bigbuf[t];
    }

    // --- h plane: 13 broadcast b128 reads (halves [0,104) of this k-half) ---
    uix4 hb[13];
    #pragma unroll
    for (int i = 0; i < 13; ++i) hb[i] = hvp[i];

    // --- dot phase: fp16 dot2, f32 accumulate ---
    float a0 = 0.f, a1 = 0.f, a2 = 0.f, a3 = 0.f, a4 = 0.f, a5 = 0.f;
    #pragma unroll
    for (int p = 0; p < 50; ++p) {
      half2v h2 = ash2(hb[p >> 2][p & 3]);
      a0 = __builtin_amdgcn_fdot2(ash2(w[0][p]), h2, a0, false);
      a1 = __builtin_amdgcn_fdot2(ash2(w[1][p]), h2, a1, false);
      a2 = __builtin_amdgcn_fdot2(ash2(w[2][p]), h2, a2, false);
      a3 = __builtin_amdgcn_fdot2(ash2(w[3][p]), h2, a3, false);
      a4 = __builtin_amdgcn_fdot2(ash2(w[4][p]), h2, a4, false);
      a5 = __builtin_amdgcn_fdot2(ash2(w[5][p]), h2, a5, false);
    }
    const int pb = kh * 804;
    parts[pb + gs]        = a0;
    parts[pb + 128 + gs]  = a1;
    parts[pb + 256 + gs]  = a2;
    parts[pb + 384 + gs]  = a3;
    parts[pb + 512 + gs]  = a4;
    parts[pb + 640 + gs]  = a5;
    if (tail) {
      float a6 = 0.f;
      #pragma unroll
      for (int p = 0; p < 50; ++p)
        a6 = __builtin_amdgcn_fdot2(ash2(wt[p]), ash2(hb[p >> 2][p & 3]), a6, false);
      parts[pb + 672 + gs] = a6;   // gate 768+(gs-96)
    }
    __syncthreads();

    // --- reduce + nonlinearity (threads 0..199) ---
    if (u < 200) {
      float gi = parts[u]       + parts[804 + u]       + bI + bfr2f(qI);
      float gf = parts[200 + u] + parts[804 + 200 + u] + bF + bfr2f(qF);
      float gg = parts[400 + u] + parts[804 + 400 + u] + bG + bfr2f(qG);
      float go = parts[600 + u] + parts[804 + 600 + u] + bO + bfr2f(qO);
      float si = sigm(gi), sf = sigm(gf), so = sigm(go);
      float cn = sf * creg + si * tanh_f(gg);
      float hn = so * tanh_f(cn);
      bool kp = (mk == 0);
      creg = kp ? cn : creg;
      hreg = kp ? hn : hreg;
      hsh[hwrite] = (_Float16)hreg;
      out[((size_t)row * T + t) * ostride + dir * H + u] =
          __float2bfloat16(kp ? hn : 0.0f);
    }
    __syncthreads();
  }

  if (final_h != nullptr && u < 200) {
    // glob_h = [hb1 | hf1]: backward dir -> cols 0..199, forward -> 200..399
    int col = dir ? u : (H + u);
    final_h[(size_t)row * 400 + col] = hreg;
  }
}

// ---------------------------------------------------------------------------
// Span sums
__global__ __launch_bounds__(256) void span_sum(
    const __hip_bfloat16* __restrict__ rnn,   // [B][T][400]
    const int* __restrict__ masks,
    const int* __restrict__ subj_pos,
    const int* __restrict__ obj_pos,
    float* __restrict__ obj_h,   // [B][400]
    float* __restrict__ subj_h)  // [B][400]
{
  int b = blockIdx.x;
  for (int d = threadIdx.x; d < 400; d += 256) {
    float ss = 0.f, so = 0.f;
    for (int t = 0; t < T; ++t) {
      int m = masks[b * T + t];
      float v = __bfloat162float(rnn[((size_t)b * T + t) * 400 + d]);
      if (subj_pos[b * T + t] + m == 0) ss += v;
      if (obj_pos[b * T + t] + m == 0) so += v;
    }
    subj_h[(size_t)b * 400 + d] = ss;
    obj_h[(size_t)b * 400 + d] = so;
  }
}

// ---------------------------------------------------------------------------
// Single-query attention pooling. grid = 3*128 (qi = blk>>7, b = blk&127)
__global__ __launch_bounds__(256) void attn_pool_k(
    const float* __restrict__ qbuf,           // [3][B][400]
    const __hip_bfloat16* __restrict__ rnn,   // [B][T][400]
    const int* __restrict__ masks,
    float* __restrict__ outp)                 // [3][B][400]
{
  int b = blockIdx.x & 127;
  int qi = blockIdx.x >> 7;
  __shared__ float qs[400];
  __shared__ float ps[256];
  __shared__ float red[256];
  const float* q = qbuf + ((size_t)qi * B + b) * 400;
  for (int d = threadIdx.x; d < 400; d += 256) qs[d] = q[d];
  __syncthreads();

  int t = threadIdx.x;
  const __hip_bfloat16* kv = rnn + ((size_t)b * T + t) * 400;
  float s = 0.f;
  for (int d = 0; d < 400; ++d) s += qs[d] * __bfloat162float(kv[d]);
  s *= 0.05f;  // 1/sqrt(400)
  if (masks[b * T + t] != 0) s = -1e9f;

  red[t] = s;
  __syncthreads();
  for (int off = 128; off > 0; off >>= 1) {
    if (t < off) red[t] = fmaxf(red[t], red[t + off]);
    __syncthreads();
  }
  float mx = red[0];
  __syncthreads();
  float e = expf(s - mx);
  red[t] = e;
  __syncthreads();
  for (int off = 128; off > 0; off >>= 1) {
    if (t < off) red[t] += red[t + off];
    __syncthreads();
  }
  float inv = 1.0f / red[0];
  ps[t] = e * inv;
  __syncthreads();

  for (int d = threadIdx.x; d < 400; d += 256) {
    float acc = 0.f;
    for (int t2 = 0; t2 < T; ++t2)
      acc += ps[t2] * __bfloat162float(rnn[((size_t)b * T + t2) * 400 + d]);
    outp[((size_t)qi * B + b) * 400 + d] = acc;
  }
}

// ---------------------------------------------------------------------------
// Head
__global__ __launch_bounds__(256) void final_head(
    const float* __restrict__ attn,   // [3][B][400]: 0=obj,1=subj,2=glob
    const __hip_bfloat16* __restrict__ wo_w, const __hip_bfloat16* __restrict__ wo_b,
    const __hip_bfloat16* __restrict__ ws_w, const __hip_bfloat16* __restrict__ ws_b,
    const __hip_bfloat16* __restrict__ wg_w, const __hip_bfloat16* __restrict__ wg_b,
    const __hip_bfloat16* __restrict__ cls_w, const __hip_bfloat16* __restrict__ cls_b,
    void* __restrict__ outp,          // [B][2]
    const int* __restrict__ flag)
{
  int b = blockIdx.x;
  __shared__ float hs[H];
  int j = threadIdx.x;
  if (j < H) {
    float acc = __bfloat162float(wo_b[j]) + __bfloat162float(ws_b[j]) +
                __bfloat162float(wg_b[j]);
    const float* oa = attn + ((size_t)0 * B + b) * 400;
    const float* sa = attn + ((size_t)1 * B + b) * 400;
    const float* ga = attn + ((size_t)2 * B + b) * 400;
    for (int d = 0; d < 400; ++d) {
      acc += oa[d] * __bfloat162float(wo_w[(size_t)j * 400 + d]);
      acc += sa[d] * __bfloat162float(ws_w[(size_t)j * 400 + d]);
      acc += ga[d] * __bfloat162float(wg_w[(size_t)j * 400 + d]);
    }
    hs[j] = fmaxf(acc, 0.0f);
  }
  __syncthreads();
  if (j < 2) {
    float a = __bfloat162float(cls_b[j]);
    for (int k = 0; k < H; ++k)
      a += hs[k] * __bfloat162float(cls_w[(size_t)j * H + k]);
    if (*flag) ((float*)outp)[b * 2 + j] = a;
    else       ((__hip_bfloat16*)outp)[b * 2 + j] = __float2bfloat16(a);
  }
}

// ---------------------------------------------------------------------------
// Workspace layout (bytes)
constexpr size_t O_X0   = 0;            // 32768*384*2  = 25165824
constexpr size_t O_X1   = 25165824;     // 32768*416*2  = 27262976
constexpr size_t O_GPRE = 52428800;     // 2*32768*800*2 = 104857600 (embC overlaid pre-GEMM)
constexpr size_t O_RNN  = 157286400;    // 32768*400*2  = 26214400
constexpr size_t O_WIH0 = 183500800;    // 2*800*384*2  = 1228800
constexpr size_t O_WIH1 = 184729600;    // 2*800*416*2  = 1331200
constexpr size_t O_WPK  = 186060800;    // 4*800*100*4  = 1280000
constexpr size_t O_Q    = 187340800;    // 3*128*400*4  = 614400
constexpr size_t O_ATT  = 187955200;    // 614400
constexpr size_t O_FLAG = 188569600;    // 256
constexpr size_t O_POSC = 188569856;
constexpr size_t O_NERC = 188572864;
constexpr size_t O_BIAS = 188574368;    // 4*800*2 = 6400
constexpr size_t O_WOW  = 188580768;    // 80000*2 = 160000
constexpr size_t O_WSW  = 188740768;
constexpr size_t O_WGW  = 188900768;
constexpr size_t O_WOB  = 189060768;
constexpr size_t O_WSB  = 189061168;
constexpr size_t O_WGB  = 189061568;
constexpr size_t O_CLSW = 189061968;
constexpr size_t O_CLSB = 189062768;

extern "C" void kernel_launch(void* const* d_in, const int* in_sizes, int n_in,
                              void* d_out, int out_size, void* d_ws, size_t ws_size,
                              hipStream_t stream) {
  (void)in_sizes; (void)n_in; (void)out_size; (void)ws_size;

  const int* words = (const int*)d_in[0];
  const int* masks = (const int*)d_in[1];
  const int* pos   = (const int*)d_in[2];
  const int* ner   = (const int*)d_in[3];
  const int* subj  = (const int*)d_in[4];
  const int* obj   = (const int*)d_in[5];
  const void* emb_w = d_in[6];
  const void* pos_w = d_in[7];
  const void* ner_w = d_in[8];
  const void* wih[4]  = {d_in[9],  d_in[12], d_in[15], d_in[18]};
  const void* whh[4]  = {d_in[10], d_in[13], d_in[16], d_in[19]};
  const void* bias[4] = {d_in[11], d_in[14], d_in[17], d_in[20]};
  const void* wo_w = d_in[21]; const void* wo_b = d_in[22];
  const void* ws_w = d_in[23]; const void* ws_b = d_in[24];
  const void* wg_w = d_in[25]; const void* wg_b = d_in[26];
  const void* cls_w = d_in[27]; const void* cls_b = d_in[28];

  char* ws = (char*)d_ws;
  __hip_bfloat16* X0   = (__hip_bfloat16*)(ws + O_X0);
  __hip_bfloat16* X1   = (__hip_bfloat16*)(ws + O_X1);
  __hip_bfloat16* Gpre = (__hip_bfloat16*)(ws + O_GPRE);
  __hip_bfloat16* embC = (__hip_bfloat16*)(ws + O_GPRE);  // overlaid (dead before GEMM)
  __hip_bfloat16* RNN  = (__hip_bfloat16*)(ws + O_RNN);
  __hip_bfloat16* wih0p = (__hip_bfloat16*)(ws + O_WIH0);  // [2][800][384]
  __hip_bfloat16* wih1p = (__hip_bfloat16*)(ws + O_WIH1);  // [2][800][416]
  unsigned* Wpack = (unsigned*)(ws + O_WPK);               // [4][800][100] fp16 pairs
  float* qbuf = (float*)(ws + O_Q);    // [3][B][400]: obj, subj, glob
  float* attb = (float*)(ws + O_ATT);  // [3][B][400]
  int* flag = (int*)(ws + O_FLAG);
  __hip_bfloat16* posC = (__hip_bfloat16*)(ws + O_POSC);
  __hip_bfloat16* nerC = (__hip_bfloat16*)(ws + O_NERC);
  __hip_bfloat16* biasC = (__hip_bfloat16*)(ws + O_BIAS);  // [4][800]
  __hip_bfloat16* woW = (__hip_bfloat16*)(ws + O_WOW);
  __hip_bfloat16* wsW = (__hip_bfloat16*)(ws + O_WSW);
  __hip_bfloat16* wgW = (__hip_bfloat16*)(ws + O_WGW);
  __hip_bfloat16* woB = (__hip_bfloat16*)(ws + O_WOB);
  __hip_bfloat16* wsB = (__hip_bfloat16*)(ws + O_WSB);
  __hip_bfloat16* wgB = (__hip_bfloat16*)(ws + O_WGB);
  __hip_bfloat16* clsW = (__hip_bfloat16*)(ws + O_CLSW);
  __hip_bfloat16* clsB = (__hip_bfloat16*)(ws + O_CLSB);

  // --- dtype detect + conversions ---
  detect_dtype<<<1, 256, 0, stream>>>((const unsigned short*)emb_w, flag);
  conv_to_bf16<<<1024, 256, 0, stream>>>(emb_w, embC, 40000 * 300, flag);
  conv_to_bf16<<<2, 256, 0, stream>>>(pos_w, posC, 50 * 30, flag);
  conv_to_bf16<<<1, 256, 0, stream>>>(ner_w, nerC, 25 * 30, flag);
  for (int i = 0; i < 4; ++i)
    conv_to_bf16<<<2, 256, 0, stream>>>(bias[i], biasC + i * G4, G4, flag);
  conv_to_bf16<<<64, 256, 0, stream>>>(wo_w, woW, H * 400, flag);
  conv_to_bf16<<<64, 256, 0, stream>>>(ws_w, wsW, H * 400, flag);
  conv_to_bf16<<<64, 256, 0, stream>>>(wg_w, wgW, H * 400, flag);
  conv_to_bf16<<<1, 256, 0, stream>>>(wo_b, woB, H, flag);
  conv_to_bf16<<<1, 256, 0, stream>>>(ws_b, wsB, H, flag);
  conv_to_bf16<<<1, 256, 0, stream>>>(wg_b, wgB, H, flag);
  conv_to_bf16<<<1, 256, 0, stream>>>(cls_w, clsW, 2 * H, flag);
  conv_to_bf16<<<1, 256, 0, stream>>>(cls_b, clsB, 2, flag);

  // --- weight prep ---
  pad_copy<<<G4, 128, 0, stream>>>(wih[0], wih0p,               K0, K0P, flag);
  pad_copy<<<G4, 128, 0, stream>>>(wih[1], wih0p + G4 * K0P,    K0, K0P, flag);
  pad_copy<<<G4, 128, 0, stream>>>(wih[2], wih1p,               K1, K1P, flag);
  pad_copy<<<G4, 128, 0, stream>>>(wih[3], wih1p + G4 * K1P,    K1, K1P, flag);
  for (int i = 0; i < 4; ++i)
    pack_whh<<<313, 256, 0, stream>>>(whh[i], Wpack + (size_t)i * G4 * 100, flag);

  // --- embedding + X1 pad ---
  embed_kernel<<<BT, 128, 0, stream>>>(words, pos, ner, embC, posC, nerC, X0);
  zero_x1_tail<<<2048, 256, 0, stream>>>(X1);

  dim3 ggrid(BT / 64, 13);

  // --- layer 0: input projections + recurrence ---
  gemm_bt<<<ggrid, 256, 0, stream>>>(X0, wih0p,            Gpre,                   G4, K0P);
  gemm_bt<<<ggrid, 256, 0, stream>>>(X0, wih0p + G4 * K0P, Gpre + (size_t)BT * G4, G4, K0P);
  lstm_row<<<256, 256, 0, stream>>>(Gpre, Wpack, biasC, biasC + G4, masks,
                                    X1, K1P, nullptr);

  // --- layer 1 ---
  gemm_bt<<<ggrid, 256, 0, stream>>>(X1, wih1p,            Gpre,                   G4, K1P);
  gemm_bt<<<ggrid, 256, 0, stream>>>(X1, wih1p + G4 * K1P, Gpre + (size_t)BT * G4, G4, K1P);
  float* qglob = qbuf + (size_t)2 * B * 400;
  lstm_row<<<256, 256, 0, stream>>>(Gpre, Wpack + (size_t)2 * G4 * 100,
                                    biasC + 2 * G4, biasC + 3 * G4, masks,
                                    RNN, 400, qglob);

  // --- span sums (obj -> slot0, subj -> slot1) ---
  span_sum<<<B, 256, 0, stream>>>(RNN, masks, subj, obj,
                                  qbuf, qbuf + (size_t)B * 400);

  // --- attention pooling (3 queries) ---
  attn_pool_k<<<3 * B, 256, 0, stream>>>(qbuf, RNN, masks, attb);

  // --- head ---
  final_head<<<B, 256, 0, stream>>>(attb, woW, woB, wsW, wsB, wgW, wgB,
                                    clsW, clsB, d_out, flag);
}

// Round 11
// 2090.958 us; speedup vs baseline: 3.4725x; 1.0242x over previous
//
#include <hip/hip_runtime.h>
#include <hip/hip_bf16.h>
#include <math.h>

// Problem constants
constexpr int B = 128;
constexpr int T = 256;
constexpr int H = 200;       // hidden
constexpr int G4 = 800;      // 4*H
constexpr int BT = B * T;    // 32768
constexpr int K0 = 360, K0P = 384;   // layer0 input dim, padded to %32
constexpr int K1 = 400, K1P = 416;   // layer1 input dim, padded to %32

typedef __bf16 bf16x8 __attribute__((ext_vector_type(8)));
typedef float f32x4 __attribute__((ext_vector_type(4)));
typedef _Float16 half2v __attribute__((ext_vector_type(2)));
typedef unsigned uix4 __attribute__((ext_vector_type(4)));

__device__ __forceinline__ float bfr2f(unsigned short u) {
  union { unsigned int i; float f; } x;
  x.i = ((unsigned int)u) << 16;
  return x.f;
}
__device__ __forceinline__ unsigned short f2hu(float f) {
  _Float16 h = (_Float16)f;
  return *(unsigned short*)&h;
}
__device__ __forceinline__ half2v ash2(unsigned u) {
  union { unsigned v; half2v h; } x;
  x.v = u;
  return x.h;
}
__device__ __forceinline__ float sigm(float x) {
  return 1.0f / (1.0f + __expf(-x));
}
__device__ __forceinline__ float tanh_f(float x) {
  float e = __expf(2.0f * x);
  return (e - 1.0f) / (e + 1.0f);
}
// flag-dispatched raw load of a "float" input (f32 or bf16 storage)
__device__ __forceinline__ float ldraw(const void* p, size_t i, int f) {
  return f ? ((const float*)p)[i] : bfr2f(((const unsigned short*)p)[i]);
}

// ---------------------------------------------------------------------------
// Dtype detector (f32 vs bf16 storage of float inputs); see round-2 notes.
__global__ void detect_dtype(const unsigned short* __restrict__ raw,
                             int* __restrict__ flag) {
  __shared__ int cnt[256];
  int c = 0;
  for (int j = 0; j < 32; ++j) {
    unsigned short u = raw[1024 + threadIdx.x * 32 + j];
    int e = (u >> 7) & 0xFF;
    if (e >= 0xC0) ++c;
  }
  cnt[threadIdx.x] = c;
  __syncthreads();
  for (int off = 128; off > 0; off >>= 1) {
    if (threadIdx.x < off) cnt[threadIdx.x] += cnt[threadIdx.x + off];
    __syncthreads();
  }
  if (threadIdx.x == 0) *flag = (cnt[0] > 16) ? 1 : 0;
}

// Zero-fill (uix4 granularity)
__global__ void fill_zero(uix4* __restrict__ p, size_t n4) {
  size_t i = (size_t)blockIdx.x * blockDim.x + threadIdx.x;
  size_t stride = (size_t)gridDim.x * blockDim.x;
  uix4 z = {0u, 0u, 0u, 0u};
  for (; i < n4; i += stride) p[i] = z;
}

// ---------------------------------------------------------------------------
// Embedding concat into X0 [BT][K0P] — reads raw tables (flag-dispatched)
__global__ void embed_kernel(const int* __restrict__ words,
                             const int* __restrict__ pos,
                             const int* __restrict__ ner,
                             const void* __restrict__ emb_w,
                             const void* __restrict__ pos_w,
                             const void* __restrict__ ner_w,
                             __hip_bfloat16* __restrict__ X0,
                             const int* __restrict__ flag) {
  int bt = blockIdx.x;
  int f = *flag;
  int w = words[bt], p = pos[bt], nr = ner[bt];
  for (int j = threadIdx.x; j < K0P; j += blockDim.x) {
    float v;
    if (j < 300)       v = ldraw(emb_w, (size_t)w * 300 + j, f);
    else if (j < 330)  v = ldraw(pos_w, (size_t)p * 30 + (j - 300), f);
    else if (j < 360)  v = ldraw(ner_w, (size_t)nr * 30 + (j - 330), f);
    else               v = 0.0f;
    X0[(size_t)bt * K0P + j] = __float2bfloat16(v);
  }
}

// Pad-copy both directions' W_ih into one stacked [1600][Kp] bf16 matrix
__global__ void pad_copy2(const void* __restrict__ srcf,
                          const void* __restrict__ srcb,
                          __hip_bfloat16* __restrict__ dst, int K, int Kp,
                          const int* __restrict__ flag) {
  int r = blockIdx.x;  // 0..1599
  int f = *flag;
  const void* src = (r < G4) ? srcf : srcb;
  int rr = (r < G4) ? r : r - G4;
  for (int j = threadIdx.x; j < Kp; j += blockDim.x) {
    float v = (j < K) ? ldraw(src, (size_t)rr * K + j, f) : 0.0f;
    dst[(size_t)r * Kp + j] = __float2bfloat16(v);
  }
}

// Pack all 4 W_hh [800][200] into k-pairwise FP16 dwords (fp16 exact for
// bf16-derived weights; enables v_dot2_f32_f16: 1 instr / 2 MACs, f32 acc).
__global__ void pack_whh4(const void* __restrict__ s0, const void* __restrict__ s1,
                          const void* __restrict__ s2, const void* __restrict__ s3,
                          unsigned* __restrict__ dst,
                          const int* __restrict__ flag) {
  int idx = blockIdx.x * blockDim.x + threadIdx.x;  // 4*800*100
  if (idx >= 4 * G4 * 100) return;
  int f = *flag;
  int m = idx / (G4 * 100);
  int loc = idx - m * (G4 * 100);
  const void* src = (m == 0) ? s0 : (m == 1) ? s1 : (m == 2) ? s2 : s3;
  int n = loc / 100, p = loc - n * 100;
  float lo_f = ldraw(src, (size_t)n * 200 + 2 * p, f);
  float hi_f = ldraw(src, (size_t)n * 200 + 2 * p + 1, f);
  dst[idx] = (unsigned)f2hu(lo_f) | ((unsigned)f2hu(hi_f) << 16);
}

// ---------------------------------------------------------------------------
// MFMA GEMM: C[M,N] = A[M,Kp] @ Bm[N,Kp]^T   (bf16 in, fp32 acc, bf16 out)
__global__ __launch_bounds__(256) void gemm_bt(
    const __hip_bfloat16* __restrict__ A,
    const __hip_bfloat16* __restrict__ Bm,
    __hip_bfloat16* __restrict__ C,
    int N, int Kp) {
  const int lane = threadIdx.x & 63;
  const int wave = threadIdx.x >> 6;
  const int l15 = lane & 15, quad = lane >> 4;
  const int m0 = blockIdx.x * 64 + (wave & 1) * 32;
  const int n0 = blockIdx.y * 64 + (wave >> 1) * 32;

  f32x4 acc[2][2] = {};

  int c0 = n0 + l15;       if (c0 > N - 1) c0 = N - 1;
  int c1 = n0 + 16 + l15;  if (c1 > N - 1) c1 = N - 1;
  const size_t ar0 = (size_t)(m0 + l15) * Kp;
  const size_t ar1 = (size_t)(m0 + 16 + l15) * Kp;
  const size_t br0 = (size_t)c0 * Kp;
  const size_t br1 = (size_t)c1 * Kp;

  for (int k0 = 0; k0 < Kp; k0 += 32) {
    int ko = k0 + quad * 8;
    bf16x8 a0 = *(const bf16x8*)(A + ar0 + ko);
    bf16x8 a1 = *(const bf16x8*)(A + ar1 + ko);
    bf16x8 b0 = *(const bf16x8*)(Bm + br0 + ko);
    bf16x8 b1 = *(const bf16x8*)(Bm + br1 + ko);
    acc[0][0] = __builtin_amdgcn_mfma_f32_16x16x32_bf16(a0, b0, acc[0][0], 0, 0, 0);
    acc[0][1] = __builtin_amdgcn_mfma_f32_16x16x32_bf16(a0, b1, acc[0][1], 0, 0, 0);
    acc[1][0] = __builtin_amdgcn_mfma_f32_16x16x32_bf16(a1, b0, acc[1][0], 0, 0, 0);
    acc[1][1] = __builtin_amdgcn_mfma_f32_16x16x32_bf16(a1, b1, acc[1][1], 0, 0, 0);
  }
  #pragma unroll
  for (int mi = 0; mi < 2; ++mi)
    #pragma unroll
    for (int ni = 0; ni < 2; ++ni)
      #pragma unroll
      for (int r = 0; r < 4; ++r) {
        int row = m0 + mi * 16 + quad * 4 + r;
        int col = n0 + ni * 16 + l15;
        if (col < N)
          C[(size_t)row * N + col] = __float2bfloat16(acc[mi][ni][r]);
      }
}

// ---------------------------------------------------------------------------
// LSTM recurrence v6 = v10 (register-resident fp16 weights + fdot2) plus:
//  - length-aware loop: lengths in [128,256]; for t>=len the masked LSTM
//    freezes state and outputs zeros -> outputs pre-zeroed by fill_zero and
//    the loop runs only len steps (forward 0..len-1, backward len-1..0).
//    ~25% fewer steps on average, and per-step mask logic disappears.
//  - Gpre is now [BT][1600] (one fused N=1600 GEMM per layer), dir in cols.
//  - biases read raw (flag-dispatched), no pre-conversion.
// Shape (verified rounds 7-10): 256 threads, >80 KB static LDS -> 1 block/CU
// -> ~512 unified VGPR+AGPR grant; 300 weight dwords/thread live in AGPRs,
// zero spill (FETCH ~= Gpre only).
__global__ __launch_bounds__(256, 1) void lstm_row(
    const __hip_bfloat16* __restrict__ Gpre,   // [B*T][1600]  x@W_ih^T (no bias)
    const unsigned* __restrict__ Wpack,        // [2][800][100] packed fp16 k-pairs
    const void* __restrict__ bias_f_raw,       // [800] raw
    const void* __restrict__ bias_b_raw,       // [800] raw
    const int* __restrict__ masks,             // [B][T], 1 = pad
    __hip_bfloat16* __restrict__ out,          // [B][T][ostride] (pre-zeroed)
    int ostride,
    float* __restrict__ final_h,               // [B][400] = [hb | hf], or nullptr
    const int* __restrict__ flag)
{
  const int tid = threadIdx.x;
  const int dir = blockIdx.x >> 7;
  const int row = blockIdx.x & 127;
  const int kh = tid & 1;            // k-half: k-pairs [kh*50, kh*50+50)
  const int gs = tid >> 1;           // 0..127
  const bool tail = (tid >= 192);    // gs in [96,128), wave 3 — wave-uniform

  __shared__ __align__(16) _Float16 hsh[224];  // h[0..99]@0, h[100..199]@112
  __shared__ float parts[2 * 804];             // [kh][gate(+4)], 6432 B
  __shared__ int lensh[256];                   // length reduce scratch
  __shared__ int bigbuf[21504];                // 86016 B: [0:3232)=tail W
                                               // (stride 101); rest pads LDS
                                               // >80KB for the reg grant

  const unsigned* wb = Wpack + (size_t)dir * G4 * 100;

  // --- stage tail-gate weights (768..799), stride 101 ---
  for (int i = tid; i < 3200; i += 256) {
    int g = i / 100, c = i - g * 100;
    bigbuf[g * 101 + c] = (int)wb[(768 + g) * 100 + c];
  }
  // --- per-row length: count of keep tokens (pads are a contiguous tail) ---
  lensh[tid] = (masks[row * T + tid] == 0) ? 1 : 0;

  // --- register weights: 300 dwords/thread, compile-time indices ---
  unsigned w[6][50];
  {
    const unsigned* s = wb + gs * 100 + kh * 50;
    #pragma unroll
    for (int j = 0; j < 6; ++j)
      #pragma unroll
      for (int p = 0; p < 50; ++p)
        w[j][p] = s[12800 * j + p];
  }
  const unsigned* wt = (const unsigned*)&bigbuf[(gs - 96) * 101 + kh * 50];

  // --- reduce-thread constants (u = hidden unit) ---
  const int u = tid;
  const int f = *flag;
  const void* braw = dir ? bias_b_raw : bias_f_raw;
  float bI = 0.f, bF = 0.f, bG = 0.f, bO = 0.f;
  if (u < 200) {
    bI = ldraw(braw, u, f);
    bF = ldraw(braw, 200 + u, f);
    bG = ldraw(braw, 400 + u, f);
    bO = ldraw(braw, 600 + u, f);
  }

  if (tid < 224) hsh[tid] = (_Float16)0.0f;   // zero incl. gap pads
  float creg = 0.0f, hreg = 0.0f;
  __syncthreads();

  // --- length tree-reduce ---
  for (int off = 128; off > 0; off >>= 1) {
    if (tid < off) lensh[tid] += lensh[tid + off];
    __syncthreads();
  }
  const int len = lensh[0];   // in [128, 256]

  const unsigned short* gp = (const unsigned short*)Gpre + dir * 800;
  const size_t gbase = (size_t)row * T;
  const uix4* hvp = (const uix4*)(hsh + kh * 112);  // 224 B offset, 16B aligned
  const int hwrite = (u < 100) ? u : (u + 12);      // gap-padded h index

  #pragma unroll 1
  for (int tt = 0; tt < len; ++tt) {
    const int t = dir ? (len - 1 - tt) : tt;
    const size_t goff = (gbase + t) * 1600;
    // prefetch gate pre-activations (consumed in the reduce phase)
    unsigned short qI = 0, qF = 0, qG = 0, qO = 0;
    if (u < 200) {
      qI = gp[goff + u];
      qF = gp[goff + 200 + u];
      qG = gp[goff + 400 + u];
      qO = gp[goff + 600 + u];
    }

    // --- h plane: 13 broadcast b128 reads of this k-half ---
    uix4 hb[13];
    #pragma unroll
    for (int i = 0; i < 13; ++i) hb[i] = hvp[i];

    // --- dot phase: fp16 dot2, f32 accumulate ---
    float a0 = 0.f, a1 = 0.f, a2 = 0.f, a3 = 0.f, a4 = 0.f, a5 = 0.f;
    #pragma unroll
    for (int p = 0; p < 50; ++p) {
      half2v h2 = ash2(hb[p >> 2][p & 3]);
      a0 = __builtin_amdgcn_fdot2(ash2(w[0][p]), h2, a0, false);
      a1 = __builtin_amdgcn_fdot2(ash2(w[1][p]), h2, a1, false);
      a2 = __builtin_amdgcn_fdot2(ash2(w[2][p]), h2, a2, false);
      a3 = __builtin_amdgcn_fdot2(ash2(w[3][p]), h2, a3, false);
      a4 = __builtin_amdgcn_fdot2(ash2(w[4][p]), h2, a4, false);
      a5 = __builtin_amdgcn_fdot2(ash2(w[5][p]), h2, a5, false);
    }
    const int pb = kh * 804;
    parts[pb + gs]        = a0;
    parts[pb + 128 + gs]  = a1;
    parts[pb + 256 + gs]  = a2;
    parts[pb + 384 + gs]  = a3;
    parts[pb + 512 + gs]  = a4;
    parts[pb + 640 + gs]  = a5;
    if (tail) {
      float a6 = 0.f;
      #pragma unroll
      for (int p = 0; p < 50; ++p)
        a6 = __builtin_amdgcn_fdot2(ash2(wt[p]), ash2(hb[p >> 2][p & 3]), a6, false);
      parts[pb + 672 + gs] = a6;   // gate 768+(gs-96)
    }
    __syncthreads();

    // --- reduce + nonlinearity (threads 0..199); no pads inside [0,len) ---
    if (u < 200) {
      float gi = parts[u]       + parts[804 + u]       + bI + bfr2f(qI);
      float gf = parts[200 + u] + parts[804 + 200 + u] + bF + bfr2f(qF);
      float gg = parts[400 + u] + parts[804 + 400 + u] + bG + bfr2f(qG);
      float go = parts[600 + u] + parts[804 + 600 + u] + bO + bfr2f(qO);
      float si = sigm(gi), sf = sigm(gf), so = sigm(go);
      float cn = sf * creg + si * tanh_f(gg);
      float hn = so * tanh_f(cn);
      creg = cn;
      hreg = hn;
      hsh[hwrite] = (_Float16)hn;
      out[((size_t)row * T + t) * ostride + dir * H + u] = __float2bfloat16(hn);
    }
    __syncthreads();
  }

  if (final_h != nullptr && u < 200) {
    // glob_h = [hb1 | hf1]: backward dir -> cols 0..199, forward -> 200..399
    int col = dir ? u : (H + u);
    final_h[(size_t)row * 400 + col] = hreg;
  }
}

// ---------------------------------------------------------------------------
// Span sums
__global__ __launch_bounds__(256) void span_sum(
    const __hip_bfloat16* __restrict__ rnn,   // [B][T][400]
    const int* __restrict__ masks,
    const int* __restrict__ subj_pos,
    const int* __restrict__ obj_pos,
    float* __restrict__ obj_h,   // [B][400]
    float* __restrict__ subj_h)  // [B][400]
{
  int b = blockIdx.x;
  for (int d = threadIdx.x; d < 400; d += 256) {
    float ss = 0.f, so = 0.f;
    for (int t = 0; t < T; ++t) {
      int m = masks[b * T + t];
      float v = __bfloat162float(rnn[((size_t)b * T + t) * 400 + d]);
      if (subj_pos[b * T + t] + m == 0) ss += v;
      if (obj_pos[b * T + t] + m == 0) so += v;
    }
    subj_h[(size_t)b * 400 + d] = ss;
    obj_h[(size_t)b * 400 + d] = so;
  }
}

// ---------------------------------------------------------------------------
// Single-query attention pooling. grid = 3*128 (qi = blk>>7, b = blk&127)
__global__ __launch_bounds__(256) void attn_pool_k(
    const float* __restrict__ qbuf,           // [3][B][400]
    const __hip_bfloat16* __restrict__ rnn,   // [B][T][400]
    const int* __restrict__ masks,
    float* __restrict__ outp)                 // [3][B][400]
{
  int b = blockIdx.x & 127;
  int qi = blockIdx.x >> 7;
  __shared__ float qs[400];
  __shared__ float ps[256];
  __shared__ float red[256];
  const float* q = qbuf + ((size_t)qi * B + b) * 400;
  for (int d = threadIdx.x; d < 400; d += 256) qs[d] = q[d];
  __syncthreads();

  int t = threadIdx.x;
  const __hip_bfloat16* kv = rnn + ((size_t)b * T + t) * 400;
  float s = 0.f;
  for (int d = 0; d < 400; ++d) s += qs[d] * __bfloat162float(kv[d]);
  s *= 0.05f;  // 1/sqrt(400)
  if (masks[b * T + t] != 0) s = -1e9f;

  red[t] = s;
  __syncthreads();
  for (int off = 128; off > 0; off >>= 1) {
    if (t < off) red[t] = fmaxf(red[t], red[t + off]);
    __syncthreads();
  }
  float mx = red[0];
  __syncthreads();
  float e = expf(s - mx);
  red[t] = e;
  __syncthreads();
  for (int off = 128; off > 0; off >>= 1) {
    if (t < off) red[t] += red[t + off];
    __syncthreads();
  }
  float inv = 1.0f / red[0];
  ps[t] = e * inv;
  __syncthreads();

  for (int d = threadIdx.x; d < 400; d += 256) {
    float acc = 0.f;
    for (int t2 = 0; t2 < T; ++t2)
      acc += ps[t2] * __bfloat162float(rnn[((size_t)b * T + t2) * 400 + d]);
    outp[((size_t)qi * B + b) * 400 + d] = acc;
  }
}

// ---------------------------------------------------------------------------
// Head — reads all weights raw (flag-dispatched), writes bf16 or f32 per flag
__global__ __launch_bounds__(256) void final_head(
    const float* __restrict__ attn,   // [3][B][400]: 0=obj,1=subj,2=glob
    const void* __restrict__ wo_w, const void* __restrict__ wo_b,
    const void* __restrict__ ws_w, const void* __restrict__ ws_b,
    const void* __restrict__ wg_w, const void* __restrict__ wg_b,
    const void* __restrict__ cls_w, const void* __restrict__ cls_b,
    void* __restrict__ outp,          // [B][2]
    const int* __restrict__ flag)
{
  int b = blockIdx.x;
  int f = *flag;
  __shared__ float hs[H];
  int j = threadIdx.x;
  if (j < H) {
    float acc = ldraw(wo_b, j, f) + ldraw(ws_b, j, f) + ldraw(wg_b, j, f);
    const float* oa = attn + ((size_t)0 * B + b) * 400;
    const float* sa = attn + ((size_t)1 * B + b) * 400;
    const float* ga = attn + ((size_t)2 * B + b) * 400;
    for (int d = 0; d < 400; ++d) {
      acc += oa[d] * ldraw(wo_w, (size_t)j * 400 + d, f);
      acc += sa[d] * ldraw(ws_w, (size_t)j * 400 + d, f);
      acc += ga[d] * ldraw(wg_w, (size_t)j * 400 + d, f);
    }
    hs[j] = fmaxf(acc, 0.0f);
  }
  __syncthreads();
  if (j < 2) {
    float a = ldraw(cls_b, j, f);
    for (int k = 0; k < H; ++k)
      a += hs[k] * ldraw(cls_w, (size_t)j * H + k, f);
    if (f) ((float*)outp)[b * 2 + j] = a;
    else   ((__hip_bfloat16*)outp)[b * 2 + j] = __float2bfloat16(a);
  }
}

// ---------------------------------------------------------------------------
// Workspace layout (bytes)
constexpr size_t O_X0   = 0;            // 32768*384*2  = 25165824
constexpr size_t O_X1   = 25165824;     // 32768*416*2  = 27262976
constexpr size_t O_GPRE = 52428800;     // 32768*1600*2 = 104857600
constexpr size_t O_RNN  = 157286400;    // 32768*400*2  = 26214400
constexpr size_t O_WIH0 = 183500800;    // 1600*384*2   = 1228800
constexpr size_t O_WIH1 = 184729600;    // 1600*416*2   = 1331200
constexpr size_t O_WPK  = 186060800;    // 4*800*100*4  = 1280000
constexpr size_t O_Q    = 187340800;    // 3*128*400*4  = 614400
constexpr size_t O_ATT  = 187955200;    // 614400
constexpr size_t O_FLAG = 188569600;    // 256

extern "C" void kernel_launch(void* const* d_in, const int* in_sizes, int n_in,
                              void* d_out, int out_size, void* d_ws, size_t ws_size,
                              hipStream_t stream) {
  (void)in_sizes; (void)n_in; (void)out_size; (void)ws_size;

  const int* words = (const int*)d_in[0];
  const int* masks = (const int*)d_in[1];
  const int* pos   = (const int*)d_in[2];
  const int* ner   = (const int*)d_in[3];
  const int* subj  = (const int*)d_in[4];
  const int* obj   = (const int*)d_in[5];
  const void* emb_w = d_in[6];
  const void* pos_w = d_in[7];
  const void* ner_w = d_in[8];
  const void* wih[4]  = {d_in[9],  d_in[12], d_in[15], d_in[18]};
  const void* whh[4]  = {d_in[10], d_in[13], d_in[16], d_in[19]};
  const void* bias[4] = {d_in[11], d_in[14], d_in[17], d_in[20]};
  const void* wo_w = d_in[21]; const void* wo_b = d_in[22];
  const void* ws_w = d_in[23]; const void* ws_b = d_in[24];
  const void* wg_w = d_in[25]; const void* wg_b = d_in[26];
  const void* cls_w = d_in[27]; const void* cls_b = d_in[28];

  char* ws = (char*)d_ws;
  __hip_bfloat16* X0   = (__hip_bfloat16*)(ws + O_X0);
  __hip_bfloat16* X1   = (__hip_bfloat16*)(ws + O_X1);
  __hip_bfloat16* Gpre = (__hip_bfloat16*)(ws + O_GPRE);   // [BT][1600]
  __hip_bfloat16* RNN  = (__hip_bfloat16*)(ws + O_RNN);
  __hip_bfloat16* wih0p = (__hip_bfloat16*)(ws + O_WIH0);  // [1600][384]
  __hip_bfloat16* wih1p = (__hip_bfloat16*)(ws + O_WIH1);  // [1600][416]
  unsigned* Wpack = (unsigned*)(ws + O_WPK);               // [4][800][100]
  float* qbuf = (float*)(ws + O_Q);    // [3][B][400]: obj, subj, glob
  float* attb = (float*)(ws + O_ATT);  // [3][B][400]
  int* flag = (int*)(ws + O_FLAG);

  // --- dtype detect + weight prep (all read raw, flag-dispatched) ---
  detect_dtype<<<1, 256, 0, stream>>>((const unsigned short*)emb_w, flag);
  pack_whh4<<<1250, 256, 0, stream>>>(whh[0], whh[1], whh[2], whh[3], Wpack, flag);
  pad_copy2<<<1600, 128, 0, stream>>>(wih[0], wih[1], wih0p, K0, K0P, flag);
  pad_copy2<<<1600, 128, 0, stream>>>(wih[2], wih[3], wih1p, K1, K1P, flag);

  // --- embedding + output-buffer zero fills (lstm skips padded steps) ---
  embed_kernel<<<BT, 128, 0, stream>>>(words, pos, ner, emb_w, pos_w, ner_w, X0, flag);
  fill_zero<<<1024, 256, 0, stream>>>((uix4*)X1, (size_t)BT * K1P * 2 / 16);
  fill_zero<<<1024, 256, 0, stream>>>((uix4*)RNN, (size_t)BT * 400 * 2 / 16);

  dim3 ggrid(BT / 64, 25);  // N = 1600 (both dirs fused)

  // --- layer 0 ---
  gemm_bt<<<ggrid, 256, 0, stream>>>(X0, wih0p, Gpre, 1600, K0P);
  lstm_row<<<256, 256, 0, stream>>>(Gpre, Wpack, bias[0], bias[1], masks,
                                    X1, K1P, nullptr, flag);

  // --- layer 1 ---
  gemm_bt<<<ggrid, 256, 0, stream>>>(X1, wih1p, Gpre, 1600, K1P);
  float* qglob = qbuf + (size_t)2 * B * 400;
  lstm_row<<<256, 256, 0, stream>>>(Gpre, Wpack + (size_t)2 * G4 * 100,
                                    bias[2], bias[3], masks,
                                    RNN, 400, qglob, flag);

  // --- span sums (obj -> slot0, subj -> slot1) ---
  span_sum<<<B, 256, 0, stream>>>(RNN, masks, subj, obj,
                                  qbuf, qbuf + (size_t)B * 400);

  // --- attention pooling (3 queries) ---
  attn_pool_k<<<3 * B, 256, 0, stream>>>(qbuf, RNN, masks, attb);

  // --- head (raw weights) ---
  final_head<<<B, 256, 0, stream>>>(attb, wo_w, wo_b, ws_w, ws_b, wg_w, wg_b,
                                    cls_w, cls_b, d_out, flag);
}